// Round 3
// baseline (1955.719 us; speedup 1.0000x reference)
//
#include <hip/hip_runtime.h>
#include <hip/hip_bf16.h>
#include <math.h>

typedef __attribute__((ext_vector_type(8))) _Float16 half8;
typedef __attribute__((ext_vector_type(4))) float floatx4;
typedef __attribute__((ext_vector_type(4))) unsigned short ushortx4;

__device__ __forceinline__ float hu2f(unsigned short u) {
    _Float16 h;
    __builtin_memcpy(&h, &u, 2);
    return (float)h;
}
__device__ __forceinline__ unsigned short f2hu(float x) {
    _Float16 h = (_Float16)x;  // v_cvt_f16_f32, RNE
    unsigned short u;
    __builtin_memcpy(&u, &h, 2);
    return u;
}
// 2-way fp16 split: a = h0 + h1 + r, |r| <= 2^-24 |a| (subtractions exact)
__device__ __forceinline__ void split2(float a, unsigned short& s0,
                                       unsigned short& s1) {
    s0 = f2hu(a);
    float r1 = a - hu2f(s0);   // exact
    s1 = f2hu(r1);
}

// global -> LDS direct copy, 16B per lane. LDS dest must be wave-uniform base.
typedef __attribute__((address_space(1))) unsigned int as1_u32;
typedef __attribute__((address_space(3))) unsigned int as3_u32;
__device__ __forceinline__ void gload16(const void* g, void* l) {
    __builtin_amdgcn_global_load_lds((const as1_u32*)g, (as3_u32*)l, 16, 0, 0);
}

// ---------------------------------------------------------------------------
// Weight transpose + 2-way fp16 split: W[Ktrue,Ntrue] fp32 -> 2 planes
// [Nalloc][Kpad] fp16, zero-filled tails.
// ---------------------------------------------------------------------------
__global__ __launch_bounds__(256) void wsplit2_kernel(
    const float* __restrict__ W, unsigned short* __restrict__ out,
    int Ktrue, int Kpad, int Ntrue, int Nalloc)
{
    __shared__ float T[32][33];
    const int tx = threadIdx.x & 31, ty = threadIdx.x >> 5;
    const int k0 = blockIdx.x * 32, n0 = blockIdx.y * 32;
#pragma unroll
    for (int i = 0; i < 4; i++) {
        int k = k0 + ty + 8 * i, n = n0 + tx;
        T[ty + 8 * i][tx] = (k < Ktrue && n < Ntrue) ? W[(size_t)k * Ntrue + n] : 0.f;
    }
    __syncthreads();
    const size_t PS = (size_t)Nalloc * Kpad;
#pragma unroll
    for (int i = 0; i < 4; i++) {
        int n = n0 + ty + 8 * i, k = k0 + tx;
        if (n < Nalloc) {
            unsigned short h0, h1;
            split2(T[tx][ty + 8 * i], h0, h1);
            size_t base = (size_t)n * Kpad + k;
            out[base] = h0;
            out[PS + base] = h1;
        }
    }
}

// ---------------------------------------------------------------------------
// Activation split: A[M,Ka] fp32 -> 2 fp16 planes [M][Kpad], zero-fill tail.
// ---------------------------------------------------------------------------
__global__ __launch_bounds__(256) void asplit2_kernel(
    const float* __restrict__ A, unsigned short* __restrict__ out,
    int Ka, int Kpad, int M)
{
    const int kq = Kpad >> 2;
    const int n = M * kq;
    int idx = blockIdx.x * 256 + threadIdx.x;
    if (idx >= n) return;
    int row = idx / kq, c4 = idx - row * kq;
    const size_t PS = (size_t)M * Kpad;
    ushortx4 o0, o1;
#pragma unroll
    for (int e = 0; e < 4; e++) {
        int col = c4 * 4 + e;
        float v = (col < Ka) ? A[(size_t)row * Ka + col] : 0.f;
        unsigned short a, b;
        split2(v, a, b);
        o0[e] = a; o1[e] = b;
    }
    size_t base = (size_t)row * Kpad + c4 * 4;
    *(ushortx4*)(out + base) = o0;
    *(ushortx4*)(out + PS + base) = o1;
}

// ---------------------------------------------------------------------------
// Pre-split 3-product fp16 MFMA GEMM (fp32-equivalent, err ~2^-23 rel):
//   C[M,N] = A @ B^T + bias, A planes [2][M][Kpad], B planes [2][Nb][Kpad].
// Round-1 proven structure: 128x128 tile, BK=32, 4 waves, per wave 4x4 of
// 16x16x32 MFMA; products A0B0 + A0B1 + A1B0 into one fp32 accumulator.
// Staging via global_load_lds w=16, linear LDS dest + pre-swizzled source,
// XOR key (row>>1)&3 on 16B slots -> 0 measured bank conflicts (r1).
// LDS 32 KiB -> up to 5 blocks/CU.
// ---------------------------------------------------------------------------
__global__ __launch_bounds__(256, 4) void mfma_gemm_h(
    const unsigned short* __restrict__ Apl,
    const unsigned short* __restrict__ Bpl,
    const float* __restrict__ bias, float* __restrict__ C,
    int M, int N, int Kpad, int Nb)
{
    __shared__ __align__(16) unsigned short As[2][128][32];
    __shared__ __align__(16) unsigned short Bs[2][128][32];

    const int tid = threadIdx.x;
    const int lane = tid & 63;
    const int wave = tid >> 6;
    const int wm = (wave & 1) * 64, wn = (wave >> 1) * 64;

    // XCD-aware bijective swizzle (all grids here are multiples of 8 blocks)
    const int gx = gridDim.x;
    const int nwg = gx * gridDim.y;
    const int id = blockIdx.y * gx + blockIdx.x;
    const int cpx = nwg >> 3;
    const int swz = (id & 7) * cpx + (id >> 3);
    const int bm = (swz / gx) * 128, bn = (swz % gx) * 128;

    const int l15 = lane & 15, q = lane >> 4;
    const size_t PSA = (size_t)M * Kpad;
    const size_t PSB = (size_t)Nb * Kpad;

    // staging: 32 chunks/block (2 mats x 2 planes x 8 row-blocks), 1 KiB each.
    // lane -> row rb+(lane>>2), physical 16B slot lane&3; source slot
    // pre-swizzled so the read-side XOR recovers linear k.
    const int srow = lane >> 2;
    const int gslot = (lane & 3) ^ ((srow >> 1) & 3);
    const int rkey = (l15 >> 1) & 3;  // read-side XOR key (row bits [2:1])

    floatx4 acc[4][4] = {};

    for (int k0 = 0; k0 < Kpad; k0 += 32) {
        // ---- stage: 8 global_load_lds per wave ----
#pragma unroll
        for (int i = 0; i < 8; i++) {
            int e = wave * 8 + i;              // 0..31
            int mat = e >> 4, p = (e >> 3) & 1, rb = (e & 7) << 4;
            if (mat == 0) {
                gload16(Apl + (size_t)p * PSA + (size_t)(bm + rb + srow) * Kpad
                            + (k0 + gslot * 8),
                        &As[p][rb][0]);
            } else {
                gload16(Bpl + (size_t)p * PSB + (size_t)(bn + rb + srow) * Kpad
                            + (k0 + gslot * 8),
                        &Bs[p][rb][0]);
            }
        }
        __syncthreads();  // compiler drains vmcnt before s_barrier

        // ---- fragments (swizzled read) + 3 products, shared accumulator ----
        half8 bfr[2][4];
#pragma unroll
        for (int p = 0; p < 2; p++)
#pragma unroll
            for (int ni = 0; ni < 4; ni++)
                bfr[p][ni] = *(const half8*)&Bs[p][wn + ni * 16 + l15][(q ^ rkey) * 8];
#pragma unroll
        for (int pa = 0; pa < 2; pa++) {
            half8 af[4];
#pragma unroll
            for (int mi = 0; mi < 4; mi++)
                af[mi] = *(const half8*)&As[pa][wm + mi * 16 + l15][(q ^ rkey) * 8];
#pragma unroll
            for (int pb = 0; pb + pa < 2; pb++) {  // (0,0),(0,1),(1,0)
#pragma unroll
                for (int mi = 0; mi < 4; mi++)
#pragma unroll
                    for (int ni = 0; ni < 4; ni++)
                        acc[mi][ni] = __builtin_amdgcn_mfma_f32_16x16x32_f16(
                            af[mi], bfr[pb][ni], acc[mi][ni], 0, 0, 0);
            }
        }
        __syncthreads();
    }

    // ---- epilogue: bias + store (C/D layout: col=lane&15, row=q*4+reg) ----
#pragma unroll
    for (int ni = 0; ni < 4; ni++) {
        int col = bn + wn + ni * 16 + l15;
        if (col >= N) continue;
        float bv = bias[col];
#pragma unroll
        for (int mi = 0; mi < 4; mi++) {
#pragma unroll
            for (int reg = 0; reg < 4; reg++) {
                int row = bm + wm + mi * 16 + q * 4 + reg;
                C[(size_t)row * N + col] = acc[mi][ni][reg] + bv;
            }
        }
    }
}

// ---------------------------------------------------------------------------
// fp32 fallback GEMM, used only if ws too small for planes.
// ---------------------------------------------------------------------------
template <bool AVEC, bool NV4>
__global__ __launch_bounds__(256) void gemm128(
    const float* __restrict__ A, const float* __restrict__ B,
    const float* __restrict__ bias, float* __restrict__ C,
    int M, int N, int Keff, int Ktrue, int Ka)
{
    __shared__ __align__(16) float Asm[16][132];
    __shared__ __align__(16) float Bsm[16][132];
    const int tid = threadIdx.x;
    const int bm = blockIdx.y * 128, bn = blockIdx.x * 128;
    const int tx = tid & 15, ty = tid >> 4;
    const int arow = tid >> 2, ac = tid & 3;
    const int bk = tid >> 4, bc = tid & 15;
    float acc[8][8] = {};
    for (int k0 = 0; k0 < Keff; k0 += 16) {
#pragma unroll
        for (int h = 0; h < 2; h++) {
            int rr = arow + h * 64;
            if (AVEC) {
                float4 v = *(const float4*)&A[(size_t)(bm + rr) * Ka + k0 + ac * 4];
                const float* pv = &v.x;
#pragma unroll
                for (int e = 0; e < 4; e++) Asm[ac * 4 + e][rr] = pv[e];
            } else {
#pragma unroll
                for (int e = 0; e < 4; e++) {
                    int kg = k0 + ac * 4 + e;
                    Asm[ac * 4 + e][rr] = (kg < Ka) ? A[(size_t)(bm + rr) * Ka + kg] : 0.f;
                }
            }
        }
        {
            int kg = k0 + bk;
            bool kok = (kg < Ktrue);
#pragma unroll
            for (int h = 0; h < 2; h++) {
                int cc = bc * 4 + h * 64;
                if (NV4) {
                    float4 v = {0.f, 0.f, 0.f, 0.f};
                    if (kok) v = *(const float4*)&B[(size_t)kg * N + bn + cc];
                    *(float4*)&Bsm[bk][cc] = v;
                } else {
#pragma unroll
                    for (int e = 0; e < 4; e++) {
                        int col = bn + cc + e;
                        Bsm[bk][cc + e] = (kok && col < N) ? B[(size_t)kg * N + col] : 0.f;
                    }
                }
            }
        }
        __syncthreads();
#pragma unroll
        for (int k = 0; k < 16; k++) {
            float4 a0 = *(const float4*)&Asm[k][ty * 4];
            float4 a1 = *(const float4*)&Asm[k][ty * 4 + 64];
            float4 b0 = *(const float4*)&Bsm[k][tx * 4];
            float4 b1 = *(const float4*)&Bsm[k][tx * 4 + 64];
            float av[8] = {a0.x, a0.y, a0.z, a0.w, a1.x, a1.y, a1.z, a1.w};
            float bv[8] = {b0.x, b0.y, b0.z, b0.w, b1.x, b1.y, b1.z, b1.w};
#pragma unroll
            for (int i = 0; i < 8; i++)
#pragma unroll
                for (int j = 0; j < 8; j++) acc[i][j] += av[i] * bv[j];
        }
        __syncthreads();
    }
#pragma unroll
    for (int i = 0; i < 8; i++) {
        int row = bm + (i < 4 ? ty * 4 + i : 64 + ty * 4 + (i - 4));
#pragma unroll
        for (int jh = 0; jh < 2; jh++)
#pragma unroll
            for (int e = 0; e < 4; e++) {
                int col = bn + jh * 64 + tx * 4 + e;
                if (NV4 || col < N)
                    C[(size_t)row * N + col] = acc[i][jh * 4 + e] + bias[col];
            }
    }
}

// ---------------------------------------------------------------------------
__global__ __launch_bounds__(256) void colstats_kernel(
    const float* __restrict__ Y, float* __restrict__ part, int N, int rows)
{
    int c = blockIdx.x * 256 + threadIdx.x;
    int r0 = blockIdx.y * rows;
    const float* p = Y + (size_t)r0 * N + c;
    float s = 0.f, s2 = 0.f;
    for (int r = 0; r < rows; r++) {
        float v = p[(size_t)r * N];
        s += v;
        s2 += v * v;
    }
    part[(size_t)(blockIdx.y * 2 + 0) * N + c] = s;
    part[(size_t)(blockIdx.y * 2 + 1) * N + c] = s2;
}

__global__ void finalize_stats_kernel(
    const float* __restrict__ part, const float* __restrict__ g,
    const float* __restrict__ be, float* __restrict__ scale,
    float* __restrict__ shift, int N, int nchunk, float invM)
{
    int c = blockIdx.x * blockDim.x + threadIdx.x;
    if (c >= N) return;
    float s = 0.f, s2 = 0.f;
    for (int i = 0; i < nchunk; i++) {
        s  += part[(size_t)(2 * i + 0) * N + c];
        s2 += part[(size_t)(2 * i + 1) * N + c];
    }
    float m = s * invM;
    float v = s2 * invM - m * m;
    if (v < 0.f) v = 0.f;
    float sc = g[c] / sqrtf(v + 1e-5f);
    scale[c] = sc;
    shift[c] = be[c] - m * sc;
}

// bn-apply; optionally also emits 2 fp16 split planes of the result
__global__ __launch_bounds__(256) void bn_apply_kernel(
    float* __restrict__ Y, const float* __restrict__ scale,
    const float* __restrict__ shift, int do_relu, int n4, int N,
    unsigned short* __restrict__ plane, size_t PS)
{
    int idx = blockIdx.x * 256 + threadIdx.x;
    if (idx >= n4) return;
    float4* Y4 = (float4*)Y;
    float4 v = Y4[idx];
    int c = (idx * 4) & (N - 1);
    v.x = v.x * scale[c + 0] + shift[c + 0];
    v.y = v.y * scale[c + 1] + shift[c + 1];
    v.z = v.z * scale[c + 2] + shift[c + 2];
    v.w = v.w * scale[c + 3] + shift[c + 3];
    if (do_relu) {
        v.x = fmaxf(v.x, 0.f); v.y = fmaxf(v.y, 0.f);
        v.z = fmaxf(v.z, 0.f); v.w = fmaxf(v.w, 0.f);
    }
    Y4[idx] = v;
    if (plane) {
        float vv[4] = {v.x, v.y, v.z, v.w};
        ushortx4 o0, o1;
#pragma unroll
        for (int e = 0; e < 4; e++) {
            unsigned short a, b;
            split2(vv[e], a, b);
            o0[e] = a; o1[e] = b;
        }
        size_t base = (size_t)idx * 4;
        *(ushortx4*)(plane + base) = o0;
        *(ushortx4*)(plane + PS + base) = o1;
    }
}

__global__ __launch_bounds__(256) void resid_relu_kernel(
    float* __restrict__ Hb, const float* __restrict__ T, int n4,
    unsigned short* __restrict__ plane, size_t PS)
{
    int idx = blockIdx.x * 256 + threadIdx.x;
    if (idx >= n4) return;
    float4 h = ((float4*)Hb)[idx];
    float4 t = ((const float4*)T)[idx];
    h.x = fmaxf(h.x + t.x, 0.f);
    h.y = fmaxf(h.y + t.y, 0.f);
    h.z = fmaxf(h.z + t.z, 0.f);
    h.w = fmaxf(h.w + t.w, 0.f);
    ((float4*)Hb)[idx] = h;
    if (plane) {
        float vv[4] = {h.x, h.y, h.z, h.w};
        ushortx4 o0, o1;
#pragma unroll
        for (int e = 0; e < 4; e++) {
            unsigned short a, b;
            split2(vv[e], a, b);
            o0[e] = a; o1[e] = b;
        }
        size_t base = (size_t)idx * 4;
        *(ushortx4*)(plane + base) = o0;
        *(ushortx4*)(plane + PS + base) = o1;
    }
}

// ---------------------------------------------------------------------------
// O = det(R)*R, R = polar(M). Jacobi on M^T M in fp64. fp32 output.
// ---------------------------------------------------------------------------
__global__ __launch_bounds__(256) void svd_kernel(
    const float* __restrict__ O3, float* __restrict__ out, int nb)
{
    int gidx = blockIdx.x * 256 + threadIdx.x;
    if (gidx >= nb * 24) return;
    int row = gidx / 24;
    int j = gidx - row * 24;
    const float* rowp = O3 + (size_t)row * 226;
    const float* src = rowp + j * 9;

    double m[3][3];
#pragma unroll
    for (int r = 0; r < 3; r++)
#pragma unroll
        for (int c = 0; c < 3; c++) m[r][c] = (double)src[r * 3 + c];

    double a[3][3];
#pragma unroll
    for (int r = 0; r < 3; r++)
#pragma unroll
        for (int c = 0; c < 3; c++) {
            double s = 0.0;
#pragma unroll
            for (int k = 0; k < 3; k++) s += m[k][r] * m[k][c];
            a[r][c] = s;
        }

    double V[3][3] = {{1, 0, 0}, {0, 1, 0}, {0, 0, 1}};
    const int PP[3] = {0, 0, 1}, QQ[3] = {1, 2, 2};
    for (int sweep = 0; sweep < 8; sweep++) {
        for (int r3 = 0; r3 < 3; r3++) {
            int p = PP[r3], q = QQ[r3];
            double apq = a[p][q];
            if (fabs(apq) < 1e-60) continue;
            double tau = (a[q][q] - a[p][p]) / (2.0 * apq);
            double t = ((tau >= 0.0) ? 1.0 : -1.0) / (fabs(tau) + sqrt(1.0 + tau * tau));
            double c = 1.0 / sqrt(1.0 + t * t);
            double s = t * c;
#pragma unroll
            for (int k = 0; k < 3; k++) {
                double xp = a[p][k], xq = a[q][k];
                a[p][k] = c * xp - s * xq;
                a[q][k] = s * xp + c * xq;
            }
#pragma unroll
            for (int k = 0; k < 3; k++) {
                double xp = a[k][p], xq = a[k][q];
                a[k][p] = c * xp - s * xq;
                a[k][q] = s * xp + c * xq;
            }
#pragma unroll
            for (int k = 0; k < 3; k++) {
                double xp = V[k][p], xq = V[k][q];
                V[k][p] = c * xp - s * xq;
                V[k][q] = s * xp + c * xq;
            }
        }
    }

    double lam[3] = {a[0][0], a[1][1], a[2][2]};
    int i3 = 0;
    if (lam[1] < lam[i3]) i3 = 1;
    if (lam[2] < lam[i3]) i3 = 2;
    int i1 = (i3 + 1) % 3, i2 = (i3 + 2) % 3;

    double v1[3], v2[3], v3[3];
#pragma unroll
    for (int k = 0; k < 3; k++) {
        v1[k] = V[k][i1];
        v2[k] = V[k][i2];
        v3[k] = V[k][i3];
    }

    double u1[3], u2[3];
#pragma unroll
    for (int r = 0; r < 3; r++)
        u1[r] = m[r][0] * v1[0] + m[r][1] * v1[1] + m[r][2] * v1[2];
    double n1 = sqrt(u1[0] * u1[0] + u1[1] * u1[1] + u1[2] * u1[2]);
    double inv1 = (n1 > 1e-150) ? 1.0 / n1 : 0.0;
#pragma unroll
    for (int r = 0; r < 3; r++) u1[r] *= inv1;

#pragma unroll
    for (int r = 0; r < 3; r++)
        u2[r] = m[r][0] * v2[0] + m[r][1] * v2[1] + m[r][2] * v2[2];
    double d12 = u1[0] * u2[0] + u1[1] * u2[1] + u1[2] * u2[2];
#pragma unroll
    for (int r = 0; r < 3; r++) u2[r] -= d12 * u1[r];
    double n2 = sqrt(u2[0] * u2[0] + u2[1] * u2[1] + u2[2] * u2[2]);
    double inv2 = (n2 > 1e-150) ? 1.0 / n2 : 0.0;
#pragma unroll
    for (int r = 0; r < 3; r++) u2[r] *= inv2;

    double detM = m[0][0] * (m[1][1] * m[2][2] - m[1][2] * m[2][1])
                - m[0][1] * (m[1][0] * m[2][2] - m[1][2] * m[2][0])
                + m[0][2] * (m[1][0] * m[2][1] - m[1][1] * m[2][0]);
    double sgn = (detM >= 0.0) ? 1.0 : -1.0;
    double detV = v1[0] * (v2[1] * v3[2] - v2[2] * v3[1])
                - v1[1] * (v2[0] * v3[2] - v2[2] * v3[0])
                + v1[2] * (v2[0] * v3[1] - v2[1] * v3[0]);
    double sv = (detV >= 0.0) ? 1.0 : -1.0;

    double u3[3];
    u3[0] = sgn * sv * (u1[1] * u2[2] - u1[2] * u2[1]);
    u3[1] = sgn * sv * (u1[2] * u2[0] - u1[0] * u2[2]);
    u3[2] = sgn * sv * (u1[0] * u2[1] - u1[1] * u2[0]);

    size_t rot_base = (size_t)gidx * 9;
    size_t beta_base = (size_t)nb * 24 * 9 + (size_t)row * 10;
#pragma unroll
    for (int r = 0; r < 3; r++)
#pragma unroll
        for (int c = 0; c < 3; c++)
            out[rot_base + r * 3 + c] =
                (float)(sgn * (u1[r] * v1[c] + u2[r] * v2[c] + u3[r] * v3[c]));

    if (j < 10) out[beta_base + j] = rowp[216 + j];
}

// ---------------------------------------------------------------------------
extern "C" void kernel_launch(void* const* d_in, const int* in_sizes, int n_in,
                              void* d_out, int out_size, void* d_ws, size_t ws_size,
                              hipStream_t stream)
{
    const float* x    = (const float*)d_in[0];
    const float* W0   = (const float*)d_in[1];
    const float* b0   = (const float*)d_in[2];
    const float* g0   = (const float*)d_in[3];
    const float* be0  = (const float*)d_in[4];
    const float* W1a  = (const float*)d_in[5];
    const float* b1a  = (const float*)d_in[6];
    const float* g1a  = (const float*)d_in[7];
    const float* be1a = (const float*)d_in[8];
    const float* W1b  = (const float*)d_in[9];
    const float* b1b  = (const float*)d_in[10];
    const float* g1b  = (const float*)d_in[11];
    const float* be1b = (const float*)d_in[12];
    const float* W2a  = (const float*)d_in[13];
    const float* b2a  = (const float*)d_in[14];
    const float* g2a  = (const float*)d_in[15];
    const float* be2a = (const float*)d_in[16];
    const float* W2b  = (const float*)d_in[17];
    const float* b2b  = (const float*)d_in[18];
    const float* g2b  = (const float*)d_in[19];
    const float* be2b = (const float*)d_in[20];
    const float* W3   = (const float*)d_in[21];
    const float* b3   = (const float*)d_in[22];

    const int M = 8192, H = 1024, K0 = 5169, K0P = 5184, NO = 226, NOP = 256;
    const int NCHUNK = 32;

    const size_t SZ_ACT  = (size_t)M * H;
    const size_t SZ_O3   = (size_t)M * NO;
    const size_t SZ_PART = (size_t)2 * NCHUNK * H;

    float* ws   = (float*)d_ws;
    float* buf0 = ws;
    float* buf1 = buf0 + SZ_ACT;
    float* buf2 = buf1 + SZ_ACT;
    float* buf3 = buf2 + SZ_ACT;
    float* part = buf3 + SZ_O3;
    float* scale = part + SZ_PART;
    float* shift = scale + H;
    size_t float_base = 3 * SZ_ACT + SZ_O3 + SZ_PART + 2 * H + 16;

    // fp16 weight planes (2 per weight), [Nalloc][Kpad]
    unsigned short* pl = (unsigned short*)(ws + float_base);
    unsigned short* w0p  = pl;
    unsigned short* w1ap = w0p  + (size_t)2 * H * K0P;
    unsigned short* w1bp = w1ap + (size_t)2 * H * H;
    unsigned short* w2ap = w1bp + (size_t)2 * H * H;
    unsigned short* w2bp = w2ap + (size_t)2 * H * H;
    unsigned short* w3p  = w2bp + (size_t)2 * H * H;
    // activation planes
    unsigned short* xp  = w3p + (size_t)2 * NOP * H;
    unsigned short* a0p = xp  + (size_t)2 * M * K0P;
    unsigned short* a1p = a0p + (size_t)2 * M * H;
    unsigned short* pend = a1p + (size_t)2 * M * H;

    size_t bytes_new = float_base * 4 + (size_t)(pend - pl) * 2;
    bool use_new = ws_size >= bytes_new;

    dim3 blk(256);
    const int n4 = M * H / 4;
    const size_t PSH = (size_t)M * H;

    auto bnstep = [&](float* Y, const float* g, const float* be, int relu,
                      unsigned short* plane) {
        colstats_kernel<<<dim3(H / 256, NCHUNK), blk, 0, stream>>>(Y, part, H, M / NCHUNK);
        finalize_stats_kernel<<<dim3(H / 256), blk, 0, stream>>>(part, g, be, scale, shift, H, NCHUNK, 1.0f / M);
        bn_apply_kernel<<<dim3(n4 / 256), blk, 0, stream>>>(Y, scale, shift, relu, n4, H, plane, PSH);
    };

    if (use_new) {
        // 1. weight planes (w3 padded to NOP rows, zero-filled)
        wsplit2_kernel<<<dim3(K0P / 32, H / 32), blk, 0, stream>>>(W0, w0p, K0, K0P, H, H);
        wsplit2_kernel<<<dim3(H / 32, H / 32), blk, 0, stream>>>(W1a, w1ap, H, H, H, H);
        wsplit2_kernel<<<dim3(H / 32, H / 32), blk, 0, stream>>>(W1b, w1bp, H, H, H, H);
        wsplit2_kernel<<<dim3(H / 32, H / 32), blk, 0, stream>>>(W2a, w2ap, H, H, H, H);
        wsplit2_kernel<<<dim3(H / 32, H / 32), blk, 0, stream>>>(W2b, w2bp, H, H, H, H);
        wsplit2_kernel<<<dim3(H / 32, NOP / 32), blk, 0, stream>>>(W3, w3p, H, H, NO, NOP);
        // 2. input planes
        asplit2_kernel<<<dim3(M * (K0P / 4) / 256), blk, 0, stream>>>(x, xp, K0, K0P, M);

        dim3 gH(H / 128, M / 128);     // 512 blocks
        dim3 gO(NOP / 128, M / 128);   // 128 blocks

        // 3. layer 0
        mfma_gemm_h<<<gH, blk, 0, stream>>>(xp, w0p, b0, buf0, M, H, K0P, H);
        bnstep(buf0, g0, be0, 1, a0p);
        // 4. block 1
        mfma_gemm_h<<<gH, blk, 0, stream>>>(a0p, w1ap, b1a, buf1, M, H, H, H);
        bnstep(buf1, g1a, be1a, 1, a1p);
        mfma_gemm_h<<<gH, blk, 0, stream>>>(a1p, w1bp, b1b, buf2, M, H, H, H);
        bnstep(buf2, g1b, be1b, 0, nullptr);
        resid_relu_kernel<<<dim3(n4 / 256), blk, 0, stream>>>(buf0, buf2, n4, a0p, PSH);
        // 5. block 2
        mfma_gemm_h<<<gH, blk, 0, stream>>>(a0p, w2ap, b2a, buf1, M, H, H, H);
        bnstep(buf1, g2a, be2a, 1, a1p);
        mfma_gemm_h<<<gH, blk, 0, stream>>>(a1p, w2bp, b2b, buf2, M, H, H, H);
        bnstep(buf2, g2b, be2b, 0, nullptr);
        resid_relu_kernel<<<dim3(n4 / 256), blk, 0, stream>>>(buf0, buf2, n4, a0p, PSH);
        // 6. final linear (B planes padded to 256 rows; C guarded to N=226)
        mfma_gemm_h<<<gO, blk, 0, stream>>>(a0p, w3p, b3, buf3, M, NO, H, NOP);
    } else {
        // fp32 fallback
        dim3 gH(H / 128, M / 128);
        dim3 gO((NO + 127) / 128, M / 128);
        gemm128<false, true><<<gH, blk, 0, stream>>>(x, W0, b0, buf0, M, H, K0P, K0, K0);
        bnstep(buf0, g0, be0, 1, nullptr);
        gemm128<true, true><<<gH, blk, 0, stream>>>(buf0, W1a, b1a, buf1, M, H, H, H, H);
        bnstep(buf1, g1a, be1a, 1, nullptr);
        gemm128<true, true><<<gH, blk, 0, stream>>>(buf1, W1b, b1b, buf2, M, H, H, H, H);
        bnstep(buf2, g1b, be1b, 0, nullptr);
        resid_relu_kernel<<<dim3(n4 / 256), blk, 0, stream>>>(buf0, buf2, n4, nullptr, 0);
        gemm128<true, true><<<gH, blk, 0, stream>>>(buf0, W2a, b2a, buf1, M, H, H, H, H);
        bnstep(buf1, g2a, be2a, 1, nullptr);
        gemm128<true, true><<<gH, blk, 0, stream>>>(buf1, W2b, b2b, buf2, M, H, H, H, H);
        bnstep(buf2, g2b, be2b, 0, nullptr);
        resid_relu_kernel<<<dim3(n4 / 256), blk, 0, stream>>>(buf0, buf2, n4, nullptr, 0);
        gemm128<true, false><<<gO, blk, 0, stream>>>(buf0, W3, b3, buf3, M, NO, H, H, H);
    }

    // SVD epilogue -> d_out (fp32: rotmat then betas)
    svd_kernel<<<dim3((M * 24 + 255) / 256), blk, 0, stream>>>(buf3, (float*)d_out, M);
}

// Round 4
// 1410.148 us; speedup vs baseline: 1.3869x; 1.3869x over previous
//
#include <hip/hip_runtime.h>
#include <hip/hip_bf16.h>
#include <math.h>

typedef __attribute__((ext_vector_type(8))) _Float16 half8;
typedef __attribute__((ext_vector_type(4))) float floatx4;
typedef __attribute__((ext_vector_type(4))) unsigned short ushortx4;

__device__ __forceinline__ float hu2f(unsigned short u) {
    _Float16 h;
    __builtin_memcpy(&h, &u, 2);
    return (float)h;
}
__device__ __forceinline__ unsigned short f2hu(float x) {
    _Float16 h = (_Float16)x;  // v_cvt_f16_f32, RNE
    unsigned short u;
    __builtin_memcpy(&u, &h, 2);
    return u;
}
// 2-way fp16 split: a = h0 + h1 + r, |r| <= 2^-24 |a| (subtractions exact)
__device__ __forceinline__ void split2(float a, unsigned short& s0,
                                       unsigned short& s1) {
    s0 = f2hu(a);
    float r1 = a - hu2f(s0);   // exact
    s1 = f2hu(r1);
}

// global -> LDS direct copy, 16B per lane. LDS dest must be wave-uniform base.
typedef __attribute__((address_space(1))) unsigned int as1_u32;
typedef __attribute__((address_space(3))) unsigned int as3_u32;
__device__ __forceinline__ void gload16(const void* g, void* l) {
    __builtin_amdgcn_global_load_lds((const as1_u32*)g, (as3_u32*)l, 16, 0, 0);
}

// ---------------------------------------------------------------------------
// Weight transpose + 2-way fp16 split: W[Ktrue,Ntrue] fp32 -> 2 planes
// [Nalloc][Kpad] fp16, zero-filled tails.
// ---------------------------------------------------------------------------
__global__ __launch_bounds__(256) void wsplit2_kernel(
    const float* __restrict__ W, unsigned short* __restrict__ out,
    int Ktrue, int Kpad, int Ntrue, int Nalloc)
{
    __shared__ float T[32][33];
    const int tx = threadIdx.x & 31, ty = threadIdx.x >> 5;
    const int k0 = blockIdx.x * 32, n0 = blockIdx.y * 32;
#pragma unroll
    for (int i = 0; i < 4; i++) {
        int k = k0 + ty + 8 * i, n = n0 + tx;
        T[ty + 8 * i][tx] = (k < Ktrue && n < Ntrue) ? W[(size_t)k * Ntrue + n] : 0.f;
    }
    __syncthreads();
    const size_t PS = (size_t)Nalloc * Kpad;
#pragma unroll
    for (int i = 0; i < 4; i++) {
        int n = n0 + ty + 8 * i, k = k0 + tx;
        if (n < Nalloc) {
            unsigned short h0, h1;
            split2(T[tx][ty + 8 * i], h0, h1);
            size_t base = (size_t)n * Kpad + k;
            out[base] = h0;
            out[PS + base] = h1;
        }
    }
}

// ---------------------------------------------------------------------------
// Activation split: A[M,Ka] fp32 -> 2 fp16 planes [M][Kpad], zero-fill tail.
// ---------------------------------------------------------------------------
__global__ __launch_bounds__(256) void asplit2_kernel(
    const float* __restrict__ A, unsigned short* __restrict__ out,
    int Ka, int Kpad, int M)
{
    const int kq = Kpad >> 2;
    const int n = M * kq;
    int idx = blockIdx.x * 256 + threadIdx.x;
    if (idx >= n) return;
    int row = idx / kq, c4 = idx - row * kq;
    const size_t PS = (size_t)M * Kpad;
    ushortx4 o0, o1;
#pragma unroll
    for (int e = 0; e < 4; e++) {
        int col = c4 * 4 + e;
        float v = (col < Ka) ? A[(size_t)row * Ka + col] : 0.f;
        unsigned short a, b;
        split2(v, a, b);
        o0[e] = a; o1[e] = b;
    }
    size_t base = (size_t)row * Kpad + c4 * 4;
    *(ushortx4*)(out + base) = o0;
    *(ushortx4*)(out + PS + base) = o1;
}

// ---------------------------------------------------------------------------
// Pre-split 3-product fp16 MFMA GEMM (fp32-equivalent, err ~2^-23 rel):
//   C[M,N] = A @ B^T + bias, A planes [2][M][Kpad], B planes [2][Nb][Kpad].
// Round-1 proven structure: 128x128 tile, BK=32, 4 waves, per wave 4x4 of
// 16x16x32 MFMA; products A0B0 + A0B1 + A1B0 into one fp32 accumulator.
// Staging via global_load_lds w=16, linear LDS dest + pre-swizzled source,
// XOR key (row>>1)&3 on 16B slots -> 0 measured bank conflicts (r1).
// LDS 32 KiB.
// launch_bounds (256,3): cap 170 regs/wave. (256,4) capped at 128 and forced
// scratch spills (r3: WRITE_SIZE 674MB, MfmaUtil halved). acc=64 AGPR +
// ~80 VGPR = ~144 fits under 170, zero spill (r1-verified budget).
// ---------------------------------------------------------------------------
__global__ __launch_bounds__(256, 3) void mfma_gemm_h(
    const unsigned short* __restrict__ Apl,
    const unsigned short* __restrict__ Bpl,
    const float* __restrict__ bias, float* __restrict__ C,
    int M, int N, int Kpad, int Nb)
{
    __shared__ __align__(16) unsigned short As[2][128][32];
    __shared__ __align__(16) unsigned short Bs[2][128][32];

    const int tid = threadIdx.x;
    const int lane = tid & 63;
    const int wave = tid >> 6;
    const int wm = (wave & 1) * 64, wn = (wave >> 1) * 64;

    // XCD-aware bijective swizzle (all grids here are multiples of 8 blocks)
    const int gx = gridDim.x;
    const int nwg = gx * gridDim.y;
    const int id = blockIdx.y * gx + blockIdx.x;
    const int cpx = nwg >> 3;
    const int swz = (id & 7) * cpx + (id >> 3);
    const int bm = (swz / gx) * 128, bn = (swz % gx) * 128;

    const int l15 = lane & 15, q = lane >> 4;
    const size_t PSA = (size_t)M * Kpad;
    const size_t PSB = (size_t)Nb * Kpad;

    // staging: 32 chunks/block (2 mats x 2 planes x 8 row-blocks), 1 KiB each.
    // lane -> row rb+(lane>>2), physical 16B slot lane&3; source slot
    // pre-swizzled so the read-side XOR recovers linear k.
    const int srow = lane >> 2;
    const int gslot = (lane & 3) ^ ((srow >> 1) & 3);
    const int rkey = (l15 >> 1) & 3;  // read-side XOR key (row bits [2:1])

    floatx4 acc[4][4] = {};

    for (int k0 = 0; k0 < Kpad; k0 += 32) {
        // ---- stage: 8 global_load_lds per wave ----
#pragma unroll
        for (int i = 0; i < 8; i++) {
            int e = wave * 8 + i;              // 0..31
            int mat = e >> 4, p = (e >> 3) & 1, rb = (e & 7) << 4;
            if (mat == 0) {
                gload16(Apl + (size_t)p * PSA + (size_t)(bm + rb + srow) * Kpad
                            + (k0 + gslot * 8),
                        &As[p][rb][0]);
            } else {
                gload16(Bpl + (size_t)p * PSB + (size_t)(bn + rb + srow) * Kpad
                            + (k0 + gslot * 8),
                        &Bs[p][rb][0]);
            }
        }
        __syncthreads();  // compiler drains vmcnt before s_barrier

        // ---- fragments (swizzled read) + 3 products, shared accumulator ----
        half8 bfr[2][4];
#pragma unroll
        for (int p = 0; p < 2; p++)
#pragma unroll
            for (int ni = 0; ni < 4; ni++)
                bfr[p][ni] = *(const half8*)&Bs[p][wn + ni * 16 + l15][(q ^ rkey) * 8];
#pragma unroll
        for (int pa = 0; pa < 2; pa++) {
            half8 af[4];
#pragma unroll
            for (int mi = 0; mi < 4; mi++)
                af[mi] = *(const half8*)&As[pa][wm + mi * 16 + l15][(q ^ rkey) * 8];
#pragma unroll
            for (int pb = 0; pb + pa < 2; pb++) {  // (0,0),(0,1),(1,0)
#pragma unroll
                for (int mi = 0; mi < 4; mi++)
#pragma unroll
                    for (int ni = 0; ni < 4; ni++)
                        acc[mi][ni] = __builtin_amdgcn_mfma_f32_16x16x32_f16(
                            af[mi], bfr[pb][ni], acc[mi][ni], 0, 0, 0);
            }
        }
        __syncthreads();
    }

    // ---- epilogue: bias + store (C/D layout: col=lane&15, row=q*4+reg) ----
#pragma unroll
    for (int ni = 0; ni < 4; ni++) {
        int col = bn + wn + ni * 16 + l15;
        if (col >= N) continue;
        float bv = bias[col];
#pragma unroll
        for (int mi = 0; mi < 4; mi++) {
#pragma unroll
            for (int reg = 0; reg < 4; reg++) {
                int row = bm + wm + mi * 16 + q * 4 + reg;
                C[(size_t)row * N + col] = acc[mi][ni][reg] + bv;
            }
        }
    }
}

// ---------------------------------------------------------------------------
// fp32 fallback GEMM, used only if ws too small for planes.
// ---------------------------------------------------------------------------
template <bool AVEC, bool NV4>
__global__ __launch_bounds__(256) void gemm128(
    const float* __restrict__ A, const float* __restrict__ B,
    const float* __restrict__ bias, float* __restrict__ C,
    int M, int N, int Keff, int Ktrue, int Ka)
{
    __shared__ __align__(16) float Asm[16][132];
    __shared__ __align__(16) float Bsm[16][132];
    const int tid = threadIdx.x;
    const int bm = blockIdx.y * 128, bn = blockIdx.x * 128;
    const int tx = tid & 15, ty = tid >> 4;
    const int arow = tid >> 2, ac = tid & 3;
    const int bk = tid >> 4, bc = tid & 15;
    float acc[8][8] = {};
    for (int k0 = 0; k0 < Keff; k0 += 16) {
#pragma unroll
        for (int h = 0; h < 2; h++) {
            int rr = arow + h * 64;
            if (AVEC) {
                float4 v = *(const float4*)&A[(size_t)(bm + rr) * Ka + k0 + ac * 4];
                const float* pv = &v.x;
#pragma unroll
                for (int e = 0; e < 4; e++) Asm[ac * 4 + e][rr] = pv[e];
            } else {
#pragma unroll
                for (int e = 0; e < 4; e++) {
                    int kg = k0 + ac * 4 + e;
                    Asm[ac * 4 + e][rr] = (kg < Ka) ? A[(size_t)(bm + rr) * Ka + kg] : 0.f;
                }
            }
        }
        {
            int kg = k0 + bk;
            bool kok = (kg < Ktrue);
#pragma unroll
            for (int h = 0; h < 2; h++) {
                int cc = bc * 4 + h * 64;
                if (NV4) {
                    float4 v = {0.f, 0.f, 0.f, 0.f};
                    if (kok) v = *(const float4*)&B[(size_t)kg * N + bn + cc];
                    *(float4*)&Bsm[bk][cc] = v;
                } else {
#pragma unroll
                    for (int e = 0; e < 4; e++) {
                        int col = bn + cc + e;
                        Bsm[bk][cc + e] = (kok && col < N) ? B[(size_t)kg * N + col] : 0.f;
                    }
                }
            }
        }
        __syncthreads();
#pragma unroll
        for (int k = 0; k < 16; k++) {
            float4 a0 = *(const float4*)&Asm[k][ty * 4];
            float4 a1 = *(const float4*)&Asm[k][ty * 4 + 64];
            float4 b0 = *(const float4*)&Bsm[k][tx * 4];
            float4 b1 = *(const float4*)&Bsm[k][tx * 4 + 64];
            float av[8] = {a0.x, a0.y, a0.z, a0.w, a1.x, a1.y, a1.z, a1.w};
            float bv[8] = {b0.x, b0.y, b0.z, b0.w, b1.x, b1.y, b1.z, b1.w};
#pragma unroll
            for (int i = 0; i < 8; i++)
#pragma unroll
                for (int j = 0; j < 8; j++) acc[i][j] += av[i] * bv[j];
        }
        __syncthreads();
    }
#pragma unroll
    for (int i = 0; i < 8; i++) {
        int row = bm + (i < 4 ? ty * 4 + i : 64 + ty * 4 + (i - 4));
#pragma unroll
        for (int jh = 0; jh < 2; jh++)
#pragma unroll
            for (int e = 0; e < 4; e++) {
                int col = bn + jh * 64 + tx * 4 + e;
                if (NV4 || col < N)
                    C[(size_t)row * N + col] = acc[i][jh * 4 + e] + bias[col];
            }
    }
}

// ---------------------------------------------------------------------------
__global__ __launch_bounds__(256) void colstats_kernel(
    const float* __restrict__ Y, float* __restrict__ part, int N, int rows)
{
    int c = blockIdx.x * 256 + threadIdx.x;
    int r0 = blockIdx.y * rows;
    const float* p = Y + (size_t)r0 * N + c;
    float s = 0.f, s2 = 0.f;
    for (int r = 0; r < rows; r++) {
        float v = p[(size_t)r * N];
        s += v;
        s2 += v * v;
    }
    part[(size_t)(blockIdx.y * 2 + 0) * N + c] = s;
    part[(size_t)(blockIdx.y * 2 + 1) * N + c] = s2;
}

__global__ void finalize_stats_kernel(
    const float* __restrict__ part, const float* __restrict__ g,
    const float* __restrict__ be, float* __restrict__ scale,
    float* __restrict__ shift, int N, int nchunk, float invM)
{
    int c = blockIdx.x * blockDim.x + threadIdx.x;
    if (c >= N) return;
    float s = 0.f, s2 = 0.f;
    for (int i = 0; i < nchunk; i++) {
        s  += part[(size_t)(2 * i + 0) * N + c];
        s2 += part[(size_t)(2 * i + 1) * N + c];
    }
    float m = s * invM;
    float v = s2 * invM - m * m;
    if (v < 0.f) v = 0.f;
    float sc = g[c] / sqrtf(v + 1e-5f);
    scale[c] = sc;
    shift[c] = be[c] - m * sc;
}

// bn-apply; optionally also emits 2 fp16 split planes of the result
__global__ __launch_bounds__(256) void bn_apply_kernel(
    float* __restrict__ Y, const float* __restrict__ scale,
    const float* __restrict__ shift, int do_relu, int n4, int N,
    unsigned short* __restrict__ plane, size_t PS)
{
    int idx = blockIdx.x * 256 + threadIdx.x;
    if (idx >= n4) return;
    float4* Y4 = (float4*)Y;
    float4 v = Y4[idx];
    int c = (idx * 4) & (N - 1);
    v.x = v.x * scale[c + 0] + shift[c + 0];
    v.y = v.y * scale[c + 1] + shift[c + 1];
    v.z = v.z * scale[c + 2] + shift[c + 2];
    v.w = v.w * scale[c + 3] + shift[c + 3];
    if (do_relu) {
        v.x = fmaxf(v.x, 0.f); v.y = fmaxf(v.y, 0.f);
        v.z = fmaxf(v.z, 0.f); v.w = fmaxf(v.w, 0.f);
    }
    Y4[idx] = v;
    if (plane) {
        float vv[4] = {v.x, v.y, v.z, v.w};
        ushortx4 o0, o1;
#pragma unroll
        for (int e = 0; e < 4; e++) {
            unsigned short a, b;
            split2(vv[e], a, b);
            o0[e] = a; o1[e] = b;
        }
        size_t base = (size_t)idx * 4;
        *(ushortx4*)(plane + base) = o0;
        *(ushortx4*)(plane + PS + base) = o1;
    }
}

__global__ __launch_bounds__(256) void resid_relu_kernel(
    float* __restrict__ Hb, const float* __restrict__ T, int n4,
    unsigned short* __restrict__ plane, size_t PS)
{
    int idx = blockIdx.x * 256 + threadIdx.x;
    if (idx >= n4) return;
    float4 h = ((float4*)Hb)[idx];
    float4 t = ((const float4*)T)[idx];
    h.x = fmaxf(h.x + t.x, 0.f);
    h.y = fmaxf(h.y + t.y, 0.f);
    h.z = fmaxf(h.z + t.z, 0.f);
    h.w = fmaxf(h.w + t.w, 0.f);
    ((float4*)Hb)[idx] = h;
    if (plane) {
        float vv[4] = {h.x, h.y, h.z, h.w};
        ushortx4 o0, o1;
#pragma unroll
        for (int e = 0; e < 4; e++) {
            unsigned short a, b;
            split2(vv[e], a, b);
            o0[e] = a; o1[e] = b;
        }
        size_t base = (size_t)idx * 4;
        *(ushortx4*)(plane + base) = o0;
        *(ushortx4*)(plane + PS + base) = o1;
    }
}

// ---------------------------------------------------------------------------
// O = det(R)*R, R = polar(M). Jacobi on M^T M in fp64. fp32 output.
// ---------------------------------------------------------------------------
__global__ __launch_bounds__(256) void svd_kernel(
    const float* __restrict__ O3, float* __restrict__ out, int nb)
{
    int gidx = blockIdx.x * 256 + threadIdx.x;
    if (gidx >= nb * 24) return;
    int row = gidx / 24;
    int j = gidx - row * 24;
    const float* rowp = O3 + (size_t)row * 226;
    const float* src = rowp + j * 9;

    double m[3][3];
#pragma unroll
    for (int r = 0; r < 3; r++)
#pragma unroll
        for (int c = 0; c < 3; c++) m[r][c] = (double)src[r * 3 + c];

    double a[3][3];
#pragma unroll
    for (int r = 0; r < 3; r++)
#pragma unroll
        for (int c = 0; c < 3; c++) {
            double s = 0.0;
#pragma unroll
            for (int k = 0; k < 3; k++) s += m[k][r] * m[k][c];
            a[r][c] = s;
        }

    double V[3][3] = {{1, 0, 0}, {0, 1, 0}, {0, 0, 1}};
    const int PP[3] = {0, 0, 1}, QQ[3] = {1, 2, 2};
    for (int sweep = 0; sweep < 8; sweep++) {
        for (int r3 = 0; r3 < 3; r3++) {
            int p = PP[r3], q = QQ[r3];
            double apq = a[p][q];
            if (fabs(apq) < 1e-60) continue;
            double tau = (a[q][q] - a[p][p]) / (2.0 * apq);
            double t = ((tau >= 0.0) ? 1.0 : -1.0) / (fabs(tau) + sqrt(1.0 + tau * tau));
            double c = 1.0 / sqrt(1.0 + t * t);
            double s = t * c;
#pragma unroll
            for (int k = 0; k < 3; k++) {
                double xp = a[p][k], xq = a[q][k];
                a[p][k] = c * xp - s * xq;
                a[q][k] = s * xp + c * xq;
            }
#pragma unroll
            for (int k = 0; k < 3; k++) {
                double xp = a[k][p], xq = a[k][q];
                a[k][p] = c * xp - s * xq;
                a[k][q] = s * xp + c * xq;
            }
#pragma unroll
            for (int k = 0; k < 3; k++) {
                double xp = V[k][p], xq = V[k][q];
                V[k][p] = c * xp - s * xq;
                V[k][q] = s * xp + c * xq;
            }
        }
    }

    double lam[3] = {a[0][0], a[1][1], a[2][2]};
    int i3 = 0;
    if (lam[1] < lam[i3]) i3 = 1;
    if (lam[2] < lam[i3]) i3 = 2;
    int i1 = (i3 + 1) % 3, i2 = (i3 + 2) % 3;

    double v1[3], v2[3], v3[3];
#pragma unroll
    for (int k = 0; k < 3; k++) {
        v1[k] = V[k][i1];
        v2[k] = V[k][i2];
        v3[k] = V[k][i3];
    }

    double u1[3], u2[3];
#pragma unroll
    for (int r = 0; r < 3; r++)
        u1[r] = m[r][0] * v1[0] + m[r][1] * v1[1] + m[r][2] * v1[2];
    double n1 = sqrt(u1[0] * u1[0] + u1[1] * u1[1] + u1[2] * u1[2]);
    double inv1 = (n1 > 1e-150) ? 1.0 / n1 : 0.0;
#pragma unroll
    for (int r = 0; r < 3; r++) u1[r] *= inv1;

#pragma unroll
    for (int r = 0; r < 3; r++)
        u2[r] = m[r][0] * v2[0] + m[r][1] * v2[1] + m[r][2] * v2[2];
    double d12 = u1[0] * u2[0] + u1[1] * u2[1] + u1[2] * u2[2];
#pragma unroll
    for (int r = 0; r < 3; r++) u2[r] -= d12 * u1[r];
    double n2 = sqrt(u2[0] * u2[0] + u2[1] * u2[1] + u2[2] * u2[2]);
    double inv2 = (n2 > 1e-150) ? 1.0 / n2 : 0.0;
#pragma unroll
    for (int r = 0; r < 3; r++) u2[r] *= inv2;

    double detM = m[0][0] * (m[1][1] * m[2][2] - m[1][2] * m[2][1])
                - m[0][1] * (m[1][0] * m[2][2] - m[1][2] * m[2][0])
                + m[0][2] * (m[1][0] * m[2][1] - m[1][1] * m[2][0]);
    double sgn = (detM >= 0.0) ? 1.0 : -1.0;
    double detV = v1[0] * (v2[1] * v3[2] - v2[2] * v3[1])
                - v1[1] * (v2[0] * v3[2] - v2[2] * v3[0])
                + v1[2] * (v2[0] * v3[1] - v2[1] * v3[0]);
    double sv = (detV >= 0.0) ? 1.0 : -1.0;

    double u3[3];
    u3[0] = sgn * sv * (u1[1] * u2[2] - u1[2] * u2[1]);
    u3[1] = sgn * sv * (u1[2] * u2[0] - u1[0] * u2[2]);
    u3[2] = sgn * sv * (u1[0] * u2[1] - u1[1] * u2[0]);

    size_t rot_base = (size_t)gidx * 9;
    size_t beta_base = (size_t)nb * 24 * 9 + (size_t)row * 10;
#pragma unroll
    for (int r = 0; r < 3; r++)
#pragma unroll
        for (int c = 0; c < 3; c++)
            out[rot_base + r * 3 + c] =
                (float)(sgn * (u1[r] * v1[c] + u2[r] * v2[c] + u3[r] * v3[c]));

    if (j < 10) out[beta_base + j] = rowp[216 + j];
}

// ---------------------------------------------------------------------------
extern "C" void kernel_launch(void* const* d_in, const int* in_sizes, int n_in,
                              void* d_out, int out_size, void* d_ws, size_t ws_size,
                              hipStream_t stream)
{
    const float* x    = (const float*)d_in[0];
    const float* W0   = (const float*)d_in[1];
    const float* b0   = (const float*)d_in[2];
    const float* g0   = (const float*)d_in[3];
    const float* be0  = (const float*)d_in[4];
    const float* W1a  = (const float*)d_in[5];
    const float* b1a  = (const float*)d_in[6];
    const float* g1a  = (const float*)d_in[7];
    const float* be1a = (const float*)d_in[8];
    const float* W1b  = (const float*)d_in[9];
    const float* b1b  = (const float*)d_in[10];
    const float* g1b  = (const float*)d_in[11];
    const float* be1b = (const float*)d_in[12];
    const float* W2a  = (const float*)d_in[13];
    const float* b2a  = (const float*)d_in[14];
    const float* g2a  = (const float*)d_in[15];
    const float* be2a = (const float*)d_in[16];
    const float* W2b  = (const float*)d_in[17];
    const float* b2b  = (const float*)d_in[18];
    const float* g2b  = (const float*)d_in[19];
    const float* be2b = (const float*)d_in[20];
    const float* W3   = (const float*)d_in[21];
    const float* b3   = (const float*)d_in[22];

    const int M = 8192, H = 1024, K0 = 5169, K0P = 5184, NO = 226, NOP = 256;
    const int NCHUNK = 32;

    const size_t SZ_ACT  = (size_t)M * H;
    const size_t SZ_O3   = (size_t)M * NO;
    const size_t SZ_PART = (size_t)2 * NCHUNK * H;

    float* ws   = (float*)d_ws;
    float* buf0 = ws;
    float* buf1 = buf0 + SZ_ACT;
    float* buf2 = buf1 + SZ_ACT;
    float* buf3 = buf2 + SZ_ACT;
    float* part = buf3 + SZ_O3;
    float* scale = part + SZ_PART;
    float* shift = scale + H;
    size_t float_base = 3 * SZ_ACT + SZ_O3 + SZ_PART + 2 * H + 16;

    // fp16 weight planes (2 per weight), [Nalloc][Kpad]
    unsigned short* pl = (unsigned short*)(ws + float_base);
    unsigned short* w0p  = pl;
    unsigned short* w1ap = w0p  + (size_t)2 * H * K0P;
    unsigned short* w1bp = w1ap + (size_t)2 * H * H;
    unsigned short* w2ap = w1bp + (size_t)2 * H * H;
    unsigned short* w2bp = w2ap + (size_t)2 * H * H;
    unsigned short* w3p  = w2bp + (size_t)2 * H * H;
    // activation planes
    unsigned short* xp  = w3p + (size_t)2 * NOP * H;
    unsigned short* a0p = xp  + (size_t)2 * M * K0P;
    unsigned short* a1p = a0p + (size_t)2 * M * H;
    unsigned short* pend = a1p + (size_t)2 * M * H;

    size_t bytes_new = float_base * 4 + (size_t)(pend - pl) * 2;
    bool use_new = ws_size >= bytes_new;

    dim3 blk(256);
    const int n4 = M * H / 4;
    const size_t PSH = (size_t)M * H;

    auto bnstep = [&](float* Y, const float* g, const float* be, int relu,
                      unsigned short* plane) {
        colstats_kernel<<<dim3(H / 256, NCHUNK), blk, 0, stream>>>(Y, part, H, M / NCHUNK);
        finalize_stats_kernel<<<dim3(H / 256), blk, 0, stream>>>(part, g, be, scale, shift, H, NCHUNK, 1.0f / M);
        bn_apply_kernel<<<dim3(n4 / 256), blk, 0, stream>>>(Y, scale, shift, relu, n4, H, plane, PSH);
    };

    if (use_new) {
        // 1. weight planes (w3 padded to NOP rows, zero-filled)
        wsplit2_kernel<<<dim3(K0P / 32, H / 32), blk, 0, stream>>>(W0, w0p, K0, K0P, H, H);
        wsplit2_kernel<<<dim3(H / 32, H / 32), blk, 0, stream>>>(W1a, w1ap, H, H, H, H);
        wsplit2_kernel<<<dim3(H / 32, H / 32), blk, 0, stream>>>(W1b, w1bp, H, H, H, H);
        wsplit2_kernel<<<dim3(H / 32, H / 32), blk, 0, stream>>>(W2a, w2ap, H, H, H, H);
        wsplit2_kernel<<<dim3(H / 32, H / 32), blk, 0, stream>>>(W2b, w2bp, H, H, H, H);
        wsplit2_kernel<<<dim3(H / 32, NOP / 32), blk, 0, stream>>>(W3, w3p, H, H, NO, NOP);
        // 2. input planes
        asplit2_kernel<<<dim3(M * (K0P / 4) / 256), blk, 0, stream>>>(x, xp, K0, K0P, M);

        dim3 gH(H / 128, M / 128);     // 512 blocks
        dim3 gO(NOP / 128, M / 128);   // 128 blocks

        // 3. layer 0
        mfma_gemm_h<<<gH, blk, 0, stream>>>(xp, w0p, b0, buf0, M, H, K0P, H);
        bnstep(buf0, g0, be0, 1, a0p);
        // 4. block 1
        mfma_gemm_h<<<gH, blk, 0, stream>>>(a0p, w1ap, b1a, buf1, M, H, H, H);
        bnstep(buf1, g1a, be1a, 1, a1p);
        mfma_gemm_h<<<gH, blk, 0, stream>>>(a1p, w1bp, b1b, buf2, M, H, H, H);
        bnstep(buf2, g1b, be1b, 0, nullptr);
        resid_relu_kernel<<<dim3(n4 / 256), blk, 0, stream>>>(buf0, buf2, n4, a0p, PSH);
        // 5. block 2
        mfma_gemm_h<<<gH, blk, 0, stream>>>(a0p, w2ap, b2a, buf1, M, H, H, H);
        bnstep(buf1, g2a, be2a, 1, a1p);
        mfma_gemm_h<<<gH, blk, 0, stream>>>(a1p, w2bp, b2b, buf2, M, H, H, H);
        bnstep(buf2, g2b, be2b, 0, nullptr);
        resid_relu_kernel<<<dim3(n4 / 256), blk, 0, stream>>>(buf0, buf2, n4, a0p, PSH);
        // 6. final linear (B planes padded to 256 rows; C guarded to N=226)
        mfma_gemm_h<<<gO, blk, 0, stream>>>(a0p, w3p, b3, buf3, M, NO, H, NOP);
    } else {
        // fp32 fallback
        dim3 gH(H / 128, M / 128);
        dim3 gO((NO + 127) / 128, M / 128);
        gemm128<false, true><<<gH, blk, 0, stream>>>(x, W0, b0, buf0, M, H, K0P, K0, K0);
        bnstep(buf0, g0, be0, 1, nullptr);
        gemm128<true, true><<<gH, blk, 0, stream>>>(buf0, W1a, b1a, buf1, M, H, H, H, H);
        bnstep(buf1, g1a, be1a, 1, nullptr);
        gemm128<true, true><<<gH, blk, 0, stream>>>(buf1, W1b, b1b, buf2, M, H, H, H, H);
        bnstep(buf2, g1b, be1b, 0, nullptr);
        resid_relu_kernel<<<dim3(n4 / 256), blk, 0, stream>>>(buf0, buf2, n4, nullptr, 0);
        gemm128<true, true><<<gH, blk, 0, stream>>>(buf0, W2a, b2a, buf1, M, H, H, H, H);
        bnstep(buf1, g2a, be2a, 1, nullptr);
        gemm128<true, true><<<gH, blk, 0, stream>>>(buf1, W2b, b2b, buf2, M, H, H, H, H);
        bnstep(buf2, g2b, be2b, 0, nullptr);
        resid_relu_kernel<<<dim3(n4 / 256), blk, 0, stream>>>(buf0, buf2, n4, nullptr, 0);
        gemm128<true, false><<<gO, blk, 0, stream>>>(buf0, W3, b3, buf3, M, NO, H, H, H);
    }

    // SVD epilogue -> d_out (fp32: rotmat then betas)
    svd_kernel<<<dim3((M * 24 + 255) / 256), blk, 0, stream>>>(buf3, (float*)d_out, M);
}

// Round 5
// 1116.086 us; speedup vs baseline: 1.7523x; 1.2635x over previous
//
#include <hip/hip_runtime.h>
#include <hip/hip_bf16.h>
#include <math.h>

typedef __attribute__((ext_vector_type(8))) _Float16 half8;
typedef __attribute__((ext_vector_type(4))) float floatx4;
typedef __attribute__((ext_vector_type(4))) unsigned short ushortx4;

__device__ __forceinline__ float hu2f(unsigned short u) {
    _Float16 h;
    __builtin_memcpy(&h, &u, 2);
    return (float)h;
}
__device__ __forceinline__ unsigned short f2hu(float x) {
    _Float16 h = (_Float16)x;  // v_cvt_f16_f32, RNE
    unsigned short u;
    __builtin_memcpy(&u, &h, 2);
    return u;
}
// 2-way fp16 split: a = h0 + h1 + r, |r| <= 2^-24 |a| (subtractions exact)
__device__ __forceinline__ void split2(float a, unsigned short& s0,
                                       unsigned short& s1) {
    s0 = f2hu(a);
    float r1 = a - hu2f(s0);   // exact
    s1 = f2hu(r1);
}

// global -> LDS direct copy, 16B per lane. LDS dest must be wave-uniform base.
typedef __attribute__((address_space(1))) unsigned int as1_u32;
typedef __attribute__((address_space(3))) unsigned int as3_u32;
__device__ __forceinline__ void gload16(const void* g, void* l) {
    __builtin_amdgcn_global_load_lds((const as1_u32*)g, (as3_u32*)l, 16, 0, 0);
}

// ---------------------------------------------------------------------------
// Weight transpose + 2-way fp16 split: W[Ktrue,Ntrue] fp32 -> 2 planes
// [Nalloc][Kpad] fp16, zero-filled tails.
// ---------------------------------------------------------------------------
__global__ __launch_bounds__(256) void wsplit2_kernel(
    const float* __restrict__ W, unsigned short* __restrict__ out,
    int Ktrue, int Kpad, int Ntrue, int Nalloc)
{
    __shared__ float T[32][33];
    const int tx = threadIdx.x & 31, ty = threadIdx.x >> 5;
    const int k0 = blockIdx.x * 32, n0 = blockIdx.y * 32;
#pragma unroll
    for (int i = 0; i < 4; i++) {
        int k = k0 + ty + 8 * i, n = n0 + tx;
        T[ty + 8 * i][tx] = (k < Ktrue && n < Ntrue) ? W[(size_t)k * Ntrue + n] : 0.f;
    }
    __syncthreads();
    const size_t PS = (size_t)Nalloc * Kpad;
#pragma unroll
    for (int i = 0; i < 4; i++) {
        int n = n0 + ty + 8 * i, k = k0 + tx;
        if (n < Nalloc) {
            unsigned short h0, h1;
            split2(T[tx][ty + 8 * i], h0, h1);
            size_t base = (size_t)n * Kpad + k;
            out[base] = h0;
            out[PS + base] = h1;
        }
    }
}

// ---------------------------------------------------------------------------
// Activation split: A[M,Ka] fp32 -> 2 fp16 planes [M][Kpad], zero-fill tail.
// ---------------------------------------------------------------------------
__global__ __launch_bounds__(256) void asplit2_kernel(
    const float* __restrict__ A, unsigned short* __restrict__ out,
    int Ka, int Kpad, int M)
{
    const int kq = Kpad >> 2;
    const int n = M * kq;
    int idx = blockIdx.x * 256 + threadIdx.x;
    if (idx >= n) return;
    int row = idx / kq, c4 = idx - row * kq;
    const size_t PS = (size_t)M * Kpad;
    ushortx4 o0, o1;
#pragma unroll
    for (int e = 0; e < 4; e++) {
        int col = c4 * 4 + e;
        float v = (col < Ka) ? A[(size_t)row * Ka + col] : 0.f;
        unsigned short a, b;
        split2(v, a, b);
        o0[e] = a; o1[e] = b;
    }
    size_t base = (size_t)row * Kpad + c4 * 4;
    *(ushortx4*)(out + base) = o0;
    *(ushortx4*)(out + PS + base) = o1;
}

// ---------------------------------------------------------------------------
// Pre-split 3-product fp16 MFMA GEMM (fp32-equivalent, err ~2^-23 rel):
//   C[M,N] = A @ B^T + bias, A planes [2][M][Kpad], B planes [2][Nb][Kpad].
// r4-proven core: 128x128 tile, BK=32, 4 waves, per wave 4x4 of 16x16x32
// MFMA; products A0B0 + A0B1 + A1B0 into one fp32 accumulator.
// Staging via global_load_lds w=16, linear LDS dest + pre-swizzled source,
// XOR key (row>>1)&3 on 16B slots -> 0 measured bank conflicts.
// NEW (r5): optional fused column-stats. When part!=nullptr, each block
// reduces its C-tile (values incl. bias, pre-relu/bn) to per-column
// (sum, sumsq) over its 128 rows and writes part[(bm/128)*2+{0,1}][col]
// -- unique slot per block, no atomics.
// launch_bounds (256,3): (256,4) capped regs at 128 -> scratch spill (r3).
// ---------------------------------------------------------------------------
__global__ __launch_bounds__(256, 3) void mfma_gemm_h(
    const unsigned short* __restrict__ Apl,
    const unsigned short* __restrict__ Bpl,
    const float* __restrict__ bias, float* __restrict__ C,
    float* __restrict__ part,
    int M, int N, int Kpad, int Nb)
{
    __shared__ __align__(16) unsigned short As[2][128][32];
    __shared__ __align__(16) unsigned short Bs[2][128][32];
    __shared__ float sstat[2][4][16][2];   // [wn-half][ni][l15][{s,s2}]

    const int tid = threadIdx.x;
    const int lane = tid & 63;
    const int wave = tid >> 6;
    const int wm = (wave & 1) * 64, wn = (wave >> 1) * 64;

    // XCD-aware bijective swizzle (all grids here are multiples of 8 blocks)
    const int gx = gridDim.x;
    const int nwg = gx * gridDim.y;
    const int id = blockIdx.y * gx + blockIdx.x;
    const int cpx = nwg >> 3;
    const int swz = (id & 7) * cpx + (id >> 3);
    const int bm = (swz / gx) * 128, bn = (swz % gx) * 128;

    const int l15 = lane & 15, q = lane >> 4;
    const size_t PSA = (size_t)M * Kpad;
    const size_t PSB = (size_t)Nb * Kpad;

    // staging: 32 chunks/block (2 mats x 2 planes x 8 row-blocks), 1 KiB each.
    const int srow = lane >> 2;
    const int gslot = (lane & 3) ^ ((srow >> 1) & 3);
    const int rkey = (l15 >> 1) & 3;  // read-side XOR key (row bits [2:1])

    floatx4 acc[4][4] = {};

    for (int k0 = 0; k0 < Kpad; k0 += 32) {
        // ---- stage: 8 global_load_lds per wave ----
#pragma unroll
        for (int i = 0; i < 8; i++) {
            int e = wave * 8 + i;              // 0..31
            int mat = e >> 4, p = (e >> 3) & 1, rb = (e & 7) << 4;
            if (mat == 0) {
                gload16(Apl + (size_t)p * PSA + (size_t)(bm + rb + srow) * Kpad
                            + (k0 + gslot * 8),
                        &As[p][rb][0]);
            } else {
                gload16(Bpl + (size_t)p * PSB + (size_t)(bn + rb + srow) * Kpad
                            + (k0 + gslot * 8),
                        &Bs[p][rb][0]);
            }
        }
        __syncthreads();  // compiler drains vmcnt before s_barrier

        // ---- fragments (swizzled read) + 3 products, shared accumulator ----
        half8 bfr[2][4];
#pragma unroll
        for (int p = 0; p < 2; p++)
#pragma unroll
            for (int ni = 0; ni < 4; ni++)
                bfr[p][ni] = *(const half8*)&Bs[p][wn + ni * 16 + l15][(q ^ rkey) * 8];
#pragma unroll
        for (int pa = 0; pa < 2; pa++) {
            half8 af[4];
#pragma unroll
            for (int mi = 0; mi < 4; mi++)
                af[mi] = *(const half8*)&As[pa][wm + mi * 16 + l15][(q ^ rkey) * 8];
#pragma unroll
            for (int pb = 0; pb + pa < 2; pb++) {  // (0,0),(0,1),(1,0)
#pragma unroll
                for (int mi = 0; mi < 4; mi++)
#pragma unroll
                    for (int ni = 0; ni < 4; ni++)
                        acc[mi][ni] = __builtin_amdgcn_mfma_f32_16x16x32_f16(
                            af[mi], bfr[pb][ni], acc[mi][ni], 0, 0, 0);
            }
        }
        __syncthreads();
    }

    // ---- epilogue: bias + store, with per-column (s, s2) accumulation ----
    float ps[4], ps2[4];
#pragma unroll
    for (int ni = 0; ni < 4; ni++) {
        int col = bn + wn + ni * 16 + l15;
        float s = 0.f, s2 = 0.f;
        if (col < N) {
            float bv = bias[col];
#pragma unroll
            for (int mi = 0; mi < 4; mi++) {
#pragma unroll
                for (int reg = 0; reg < 4; reg++) {
                    int row = bm + wm + mi * 16 + q * 4 + reg;
                    float v = acc[mi][ni][reg] + bv;
                    C[(size_t)row * N + col] = v;
                    s += v;
                    s2 += v * v;
                }
            }
        }
        ps[ni] = s; ps2[ni] = s2;
    }

    if (part) {  // uniform branch
        // reduce over q (lanes xor 16, 32): wave-level 64-row column sums
#pragma unroll
        for (int ni = 0; ni < 4; ni++) {
            ps[ni]  += __shfl_xor(ps[ni], 16);  ps[ni]  += __shfl_xor(ps[ni], 32);
            ps2[ni] += __shfl_xor(ps2[ni], 16); ps2[ni] += __shfl_xor(ps2[ni], 32);
        }
        if (q == 0 && (wave & 1) == 1) {  // wm=64 waves publish
#pragma unroll
            for (int ni = 0; ni < 4; ni++) {
                sstat[wave >> 1][ni][l15][0] = ps[ni];
                sstat[wave >> 1][ni][l15][1] = ps2[ni];
            }
        }
        __syncthreads();
        if (q == 0 && (wave & 1) == 0) {  // wm=0 waves combine + write
            int chunk = bm >> 7;
#pragma unroll
            for (int ni = 0; ni < 4; ni++) {
                int col = bn + wn + ni * 16 + l15;
                float s  = ps[ni]  + sstat[wave >> 1][ni][l15][0];
                float s2 = ps2[ni] + sstat[wave >> 1][ni][l15][1];
                part[(size_t)(chunk * 2 + 0) * N + col] = s;
                part[(size_t)(chunk * 2 + 1) * N + col] = s2;
            }
        }
    }
}

// ---------------------------------------------------------------------------
// fp32 fallback GEMM, used only if ws too small for planes.
// ---------------------------------------------------------------------------
template <bool AVEC, bool NV4>
__global__ __launch_bounds__(256) void gemm128(
    const float* __restrict__ A, const float* __restrict__ B,
    const float* __restrict__ bias, float* __restrict__ C,
    int M, int N, int Keff, int Ktrue, int Ka)
{
    __shared__ __align__(16) float Asm[16][132];
    __shared__ __align__(16) float Bsm[16][132];
    const int tid = threadIdx.x;
    const int bm = blockIdx.y * 128, bn = blockIdx.x * 128;
    const int tx = tid & 15, ty = tid >> 4;
    const int arow = tid >> 2, ac = tid & 3;
    const int bk = tid >> 4, bc = tid & 15;
    float acc[8][8] = {};
    for (int k0 = 0; k0 < Keff; k0 += 16) {
#pragma unroll
        for (int h = 0; h < 2; h++) {
            int rr = arow + h * 64;
            if (AVEC) {
                float4 v = *(const float4*)&A[(size_t)(bm + rr) * Ka + k0 + ac * 4];
                const float* pv = &v.x;
#pragma unroll
                for (int e = 0; e < 4; e++) Asm[ac * 4 + e][rr] = pv[e];
            } else {
#pragma unroll
                for (int e = 0; e < 4; e++) {
                    int kg = k0 + ac * 4 + e;
                    Asm[ac * 4 + e][rr] = (kg < Ka) ? A[(size_t)(bm + rr) * Ka + kg] : 0.f;
                }
            }
        }
        {
            int kg = k0 + bk;
            bool kok = (kg < Ktrue);
#pragma unroll
            for (int h = 0; h < 2; h++) {
                int cc = bc * 4 + h * 64;
                if (NV4) {
                    float4 v = {0.f, 0.f, 0.f, 0.f};
                    if (kok) v = *(const float4*)&B[(size_t)kg * N + bn + cc];
                    *(float4*)&Bsm[bk][cc] = v;
                } else {
#pragma unroll
                    for (int e = 0; e < 4; e++) {
                        int col = bn + cc + e;
                        Bsm[bk][cc + e] = (kok && col < N) ? B[(size_t)kg * N + col] : 0.f;
                    }
                }
            }
        }
        __syncthreads();
#pragma unroll
        for (int k = 0; k < 16; k++) {
            float4 a0 = *(const float4*)&Asm[k][ty * 4];
            float4 a1 = *(const float4*)&Asm[k][ty * 4 + 64];
            float4 b0 = *(const float4*)&Bsm[k][tx * 4];
            float4 b1 = *(const float4*)&Bsm[k][tx * 4 + 64];
            float av[8] = {a0.x, a0.y, a0.z, a0.w, a1.x, a1.y, a1.z, a1.w};
            float bv[8] = {b0.x, b0.y, b0.z, b0.w, b1.x, b1.y, b1.z, b1.w};
#pragma unroll
            for (int i = 0; i < 8; i++)
#pragma unroll
                for (int j = 0; j < 8; j++) acc[i][j] += av[i] * bv[j];
        }
        __syncthreads();
    }
#pragma unroll
    for (int i = 0; i < 8; i++) {
        int row = bm + (i < 4 ? ty * 4 + i : 64 + ty * 4 + (i - 4));
#pragma unroll
        for (int jh = 0; jh < 2; jh++)
#pragma unroll
            for (int e = 0; e < 4; e++) {
                int col = bn + jh * 64 + tx * 4 + e;
                if (NV4 || col < N)
                    C[(size_t)row * N + col] = acc[i][jh * 4 + e] + bias[col];
            }
    }
}

// ---------------------------------------------------------------------------
__global__ __launch_bounds__(256) void colstats_kernel(
    const float* __restrict__ Y, float* __restrict__ part, int N, int rows)
{
    int c = blockIdx.x * 256 + threadIdx.x;
    int r0 = blockIdx.y * rows;
    const float* p = Y + (size_t)r0 * N + c;
    float s = 0.f, s2 = 0.f;
    for (int r = 0; r < rows; r++) {
        float v = p[(size_t)r * N];
        s += v;
        s2 += v * v;
    }
    part[(size_t)(blockIdx.y * 2 + 0) * N + c] = s;
    part[(size_t)(blockIdx.y * 2 + 1) * N + c] = s2;
}

__global__ void finalize_stats_kernel(
    const float* __restrict__ part, const float* __restrict__ g,
    const float* __restrict__ be, float* __restrict__ scale,
    float* __restrict__ shift, int N, int nchunk, float invM)
{
    int c = blockIdx.x * blockDim.x + threadIdx.x;
    if (c >= N) return;
    float s = 0.f, s2 = 0.f;
    for (int i = 0; i < nchunk; i++) {
        s  += part[(size_t)(2 * i + 0) * N + c];
        s2 += part[(size_t)(2 * i + 1) * N + c];
    }
    float m = s * invM;
    float v = s2 * invM - m * m;
    if (v < 0.f) v = 0.f;
    float sc = g[c] / sqrtf(v + 1e-5f);
    scale[c] = sc;
    shift[c] = be[c] - m * sc;
}

// bn-apply; optional fp32 write-back (write_y) and fp16 plane emission
__global__ __launch_bounds__(256) void bn_apply_kernel(
    float* __restrict__ Y, const float* __restrict__ scale,
    const float* __restrict__ shift, int do_relu, int write_y, int n4, int N,
    unsigned short* __restrict__ plane, size_t PS)
{
    int idx = blockIdx.x * 256 + threadIdx.x;
    if (idx >= n4) return;
    float4* Y4 = (float4*)Y;
    float4 v = Y4[idx];
    int c = (idx * 4) & (N - 1);
    v.x = v.x * scale[c + 0] + shift[c + 0];
    v.y = v.y * scale[c + 1] + shift[c + 1];
    v.z = v.z * scale[c + 2] + shift[c + 2];
    v.w = v.w * scale[c + 3] + shift[c + 3];
    if (do_relu) {
        v.x = fmaxf(v.x, 0.f); v.y = fmaxf(v.y, 0.f);
        v.z = fmaxf(v.z, 0.f); v.w = fmaxf(v.w, 0.f);
    }
    if (write_y) Y4[idx] = v;
    if (plane) {
        float vv[4] = {v.x, v.y, v.z, v.w};
        ushortx4 o0, o1;
#pragma unroll
        for (int e = 0; e < 4; e++) {
            unsigned short a, b;
            split2(vv[e], a, b);
            o0[e] = a; o1[e] = b;
        }
        size_t base = (size_t)idx * 4;
        *(ushortx4*)(plane + base) = o0;
        *(ushortx4*)(plane + PS + base) = o1;
    }
}

// fused: H = relu(H + bn(T)); emits planes of H. Replaces bn_apply(T)+resid.
__global__ __launch_bounds__(256) void bn_resid_relu_kernel(
    float* __restrict__ Hb, const float* __restrict__ T,
    const float* __restrict__ scale, const float* __restrict__ shift,
    int n4, int N, unsigned short* __restrict__ plane, size_t PS)
{
    int idx = blockIdx.x * 256 + threadIdx.x;
    if (idx >= n4) return;
    float4 h = ((float4*)Hb)[idx];
    float4 t = ((const float4*)T)[idx];
    int c = (idx * 4) & (N - 1);
    t.x = t.x * scale[c + 0] + shift[c + 0];
    t.y = t.y * scale[c + 1] + shift[c + 1];
    t.z = t.z * scale[c + 2] + shift[c + 2];
    t.w = t.w * scale[c + 3] + shift[c + 3];
    h.x = fmaxf(h.x + t.x, 0.f);
    h.y = fmaxf(h.y + t.y, 0.f);
    h.z = fmaxf(h.z + t.z, 0.f);
    h.w = fmaxf(h.w + t.w, 0.f);
    ((float4*)Hb)[idx] = h;
    if (plane) {
        float vv[4] = {h.x, h.y, h.z, h.w};
        ushortx4 o0, o1;
#pragma unroll
        for (int e = 0; e < 4; e++) {
            unsigned short a, b;
            split2(vv[e], a, b);
            o0[e] = a; o1[e] = b;
        }
        size_t base = (size_t)idx * 4;
        *(ushortx4*)(plane + base) = o0;
        *(ushortx4*)(plane + PS + base) = o1;
    }
}

__global__ __launch_bounds__(256) void resid_relu_kernel(
    float* __restrict__ Hb, const float* __restrict__ T, int n4,
    unsigned short* __restrict__ plane, size_t PS)
{
    int idx = blockIdx.x * 256 + threadIdx.x;
    if (idx >= n4) return;
    float4 h = ((float4*)Hb)[idx];
    float4 t = ((const float4*)T)[idx];
    h.x = fmaxf(h.x + t.x, 0.f);
    h.y = fmaxf(h.y + t.y, 0.f);
    h.z = fmaxf(h.z + t.z, 0.f);
    h.w = fmaxf(h.w + t.w, 0.f);
    ((float4*)Hb)[idx] = h;
    if (plane) {
        float vv[4] = {h.x, h.y, h.z, h.w};
        ushortx4 o0, o1;
#pragma unroll
        for (int e = 0; e < 4; e++) {
            unsigned short a, b;
            split2(vv[e], a, b);
            o0[e] = a; o1[e] = b;
        }
        size_t base = (size_t)idx * 4;
        *(ushortx4*)(plane + base) = o0;
        *(ushortx4*)(plane + PS + base) = o1;
    }
}

// ---------------------------------------------------------------------------
// O = det(R)*R, R = polar(M). Jacobi on M^T M in fp64. fp32 output.
// ---------------------------------------------------------------------------
__global__ __launch_bounds__(256) void svd_kernel(
    const float* __restrict__ O3, float* __restrict__ out, int nb)
{
    int gidx = blockIdx.x * 256 + threadIdx.x;
    if (gidx >= nb * 24) return;
    int row = gidx / 24;
    int j = gidx - row * 24;
    const float* rowp = O3 + (size_t)row * 226;
    const float* src = rowp + j * 9;

    double m[3][3];
#pragma unroll
    for (int r = 0; r < 3; r++)
#pragma unroll
        for (int c = 0; c < 3; c++) m[r][c] = (double)src[r * 3 + c];

    double a[3][3];
#pragma unroll
    for (int r = 0; r < 3; r++)
#pragma unroll
        for (int c = 0; c < 3; c++) {
            double s = 0.0;
#pragma unroll
            for (int k = 0; k < 3; k++) s += m[k][r] * m[k][c];
            a[r][c] = s;
        }

    double V[3][3] = {{1, 0, 0}, {0, 1, 0}, {0, 0, 1}};
    const int PP[3] = {0, 0, 1}, QQ[3] = {1, 2, 2};
    for (int sweep = 0; sweep < 8; sweep++) {
        for (int r3 = 0; r3 < 3; r3++) {
            int p = PP[r3], q = QQ[r3];
            double apq = a[p][q];
            if (fabs(apq) < 1e-60) continue;
            double tau = (a[q][q] - a[p][p]) / (2.0 * apq);
            double t = ((tau >= 0.0) ? 1.0 : -1.0) / (fabs(tau) + sqrt(1.0 + tau * tau));
            double c = 1.0 / sqrt(1.0 + t * t);
            double s = t * c;
#pragma unroll
            for (int k = 0; k < 3; k++) {
                double xp = a[p][k], xq = a[q][k];
                a[p][k] = c * xp - s * xq;
                a[q][k] = s * xp + c * xq;
            }
#pragma unroll
            for (int k = 0; k < 3; k++) {
                double xp = a[k][p], xq = a[k][q];
                a[k][p] = c * xp - s * xq;
                a[k][q] = s * xp + c * xq;
            }
#pragma unroll
            for (int k = 0; k < 3; k++) {
                double xp = V[k][p], xq = V[k][q];
                V[k][p] = c * xp - s * xq;
                V[k][q] = s * xp + c * xq;
            }
        }
    }

    double lam[3] = {a[0][0], a[1][1], a[2][2]};
    int i3 = 0;
    if (lam[1] < lam[i3]) i3 = 1;
    if (lam[2] < lam[i3]) i3 = 2;
    int i1 = (i3 + 1) % 3, i2 = (i3 + 2) % 3;

    double v1[3], v2[3], v3[3];
#pragma unroll
    for (int k = 0; k < 3; k++) {
        v1[k] = V[k][i1];
        v2[k] = V[k][i2];
        v3[k] = V[k][i3];
    }

    double u1[3], u2[3];
#pragma unroll
    for (int r = 0; r < 3; r++)
        u1[r] = m[r][0] * v1[0] + m[r][1] * v1[1] + m[r][2] * v1[2];
    double n1 = sqrt(u1[0] * u1[0] + u1[1] * u1[1] + u1[2] * u1[2]);
    double inv1 = (n1 > 1e-150) ? 1.0 / n1 : 0.0;
#pragma unroll
    for (int r = 0; r < 3; r++) u1[r] *= inv1;

#pragma unroll
    for (int r = 0; r < 3; r++)
        u2[r] = m[r][0] * v2[0] + m[r][1] * v2[1] + m[r][2] * v2[2];
    double d12 = u1[0] * u2[0] + u1[1] * u2[1] + u1[2] * u2[2];
#pragma unroll
    for (int r = 0; r < 3; r++) u2[r] -= d12 * u1[r];
    double n2 = sqrt(u2[0] * u2[0] + u2[1] * u2[1] + u2[2] * u2[2]);
    double inv2 = (n2 > 1e-150) ? 1.0 / n2 : 0.0;
#pragma unroll
    for (int r = 0; r < 3; r++) u2[r] *= inv2;

    double detM = m[0][0] * (m[1][1] * m[2][2] - m[1][2] * m[2][1])
                - m[0][1] * (m[1][0] * m[2][2] - m[1][2] * m[2][0])
                + m[0][2] * (m[1][0] * m[2][1] - m[1][1] * m[2][0]);
    double sgn = (detM >= 0.0) ? 1.0 : -1.0;
    double detV = v1[0] * (v2[1] * v3[2] - v2[2] * v3[1])
                - v1[1] * (v2[0] * v3[2] - v2[2] * v3[0])
                + v1[2] * (v2[0] * v3[1] - v2[1] * v3[0]);
    double sv = (detV >= 0.0) ? 1.0 : -1.0;

    double u3[3];
    u3[0] = sgn * sv * (u1[1] * u2[2] - u1[2] * u2[1]);
    u3[1] = sgn * sv * (u1[2] * u2[0] - u1[0] * u2[2]);
    u3[2] = sgn * sv * (u1[0] * u2[1] - u1[1] * u2[0]);

    size_t rot_base = (size_t)gidx * 9;
    size_t beta_base = (size_t)nb * 24 * 9 + (size_t)row * 10;
#pragma unroll
    for (int r = 0; r < 3; r++)
#pragma unroll
        for (int c = 0; c < 3; c++)
            out[rot_base + r * 3 + c] =
                (float)(sgn * (u1[r] * v1[c] + u2[r] * v2[c] + u3[r] * v3[c]));

    if (j < 10) out[beta_base + j] = rowp[216 + j];
}

// ---------------------------------------------------------------------------
extern "C" void kernel_launch(void* const* d_in, const int* in_sizes, int n_in,
                              void* d_out, int out_size, void* d_ws, size_t ws_size,
                              hipStream_t stream)
{
    const float* x    = (const float*)d_in[0];
    const float* W0   = (const float*)d_in[1];
    const float* b0   = (const float*)d_in[2];
    const float* g0   = (const float*)d_in[3];
    const float* be0  = (const float*)d_in[4];
    const float* W1a  = (const float*)d_in[5];
    const float* b1a  = (const float*)d_in[6];
    const float* g1a  = (const float*)d_in[7];
    const float* be1a = (const float*)d_in[8];
    const float* W1b  = (const float*)d_in[9];
    const float* b1b  = (const float*)d_in[10];
    const float* g1b  = (const float*)d_in[11];
    const float* be1b = (const float*)d_in[12];
    const float* W2a  = (const float*)d_in[13];
    const float* b2a  = (const float*)d_in[14];
    const float* g2a  = (const float*)d_in[15];
    const float* be2a = (const float*)d_in[16];
    const float* W2b  = (const float*)d_in[17];
    const float* b2b  = (const float*)d_in[18];
    const float* g2b  = (const float*)d_in[19];
    const float* be2b = (const float*)d_in[20];
    const float* W3   = (const float*)d_in[21];
    const float* b3   = (const float*)d_in[22];

    const int M = 8192, H = 1024, K0 = 5169, K0P = 5184, NO = 226, NOP = 256;
    const int NCH_NEW = 64;   // row-chunks from GEMM-fused stats (M/128)
    const int NCH_OLD = 32;   // fallback colstats chunking

    const size_t SZ_ACT  = (size_t)M * H;
    const size_t SZ_O3   = (size_t)M * NO;
    const size_t SZ_PART = (size_t)2 * NCH_NEW * H;

    float* ws   = (float*)d_ws;
    float* buf0 = ws;
    float* buf1 = buf0 + SZ_ACT;
    float* buf2 = buf1 + SZ_ACT;
    float* buf3 = buf2 + SZ_ACT;
    float* part = buf3 + SZ_O3;
    float* scale = part + SZ_PART;
    float* shift = scale + H;
    size_t float_base = 3 * SZ_ACT + SZ_O3 + SZ_PART + 2 * H + 16;

    // fp16 weight planes (2 per weight), [Nalloc][Kpad]
    unsigned short* pl = (unsigned short*)(ws + float_base);
    unsigned short* w0p  = pl;
    unsigned short* w1ap = w0p  + (size_t)2 * H * K0P;
    unsigned short* w1bp = w1ap + (size_t)2 * H * H;
    unsigned short* w2ap = w1bp + (size_t)2 * H * H;
    unsigned short* w2bp = w2ap + (size_t)2 * H * H;
    unsigned short* w3p  = w2bp + (size_t)2 * H * H;
    // activation planes
    unsigned short* xp  = w3p + (size_t)2 * NOP * H;
    unsigned short* a0p = xp  + (size_t)2 * M * K0P;
    unsigned short* a1p = a0p + (size_t)2 * M * H;
    unsigned short* pend = a1p + (size_t)2 * M * H;

    size_t bytes_new = float_base * 4 + (size_t)(pend - pl) * 2;
    bool use_new = ws_size >= bytes_new;

    dim3 blk(256);
    const int n4 = M * H / 4;
    const size_t PSH = (size_t)M * H;

    if (use_new) {
        // 1. weight planes (w3 padded to NOP rows, zero-filled)
        wsplit2_kernel<<<dim3(K0P / 32, H / 32), blk, 0, stream>>>(W0, w0p, K0, K0P, H, H);
        wsplit2_kernel<<<dim3(H / 32, H / 32), blk, 0, stream>>>(W1a, w1ap, H, H, H, H);
        wsplit2_kernel<<<dim3(H / 32, H / 32), blk, 0, stream>>>(W1b, w1bp, H, H, H, H);
        wsplit2_kernel<<<dim3(H / 32, H / 32), blk, 0, stream>>>(W2a, w2ap, H, H, H, H);
        wsplit2_kernel<<<dim3(H / 32, H / 32), blk, 0, stream>>>(W2b, w2bp, H, H, H, H);
        wsplit2_kernel<<<dim3(H / 32, NOP / 32), blk, 0, stream>>>(W3, w3p, H, H, NO, NOP);
        // 2. input planes
        asplit2_kernel<<<dim3(M * (K0P / 4) / 256), blk, 0, stream>>>(x, xp, K0, K0P, M);

        dim3 gH(H / 128, M / 128);     // 512 blocks
        dim3 gO(NOP / 128, M / 128);   // 128 blocks

        auto fin = [&](const float* g, const float* be) {
            finalize_stats_kernel<<<dim3(H / 256), blk, 0, stream>>>(
                part, g, be, scale, shift, H, NCH_NEW, 1.0f / M);
        };

        // 3. layer 0
        mfma_gemm_h<<<gH, blk, 0, stream>>>(xp, w0p, b0, buf0, part, M, H, K0P, H);
        fin(g0, be0);
        bn_apply_kernel<<<dim3(n4 / 256), blk, 0, stream>>>(buf0, scale, shift, 1, 1, n4, H, a0p, PSH);
        // 4. block 1
        mfma_gemm_h<<<gH, blk, 0, stream>>>(a0p, w1ap, b1a, buf1, part, M, H, H, H);
        fin(g1a, be1a);
        bn_apply_kernel<<<dim3(n4 / 256), blk, 0, stream>>>(buf1, scale, shift, 1, 0, n4, H, a1p, PSH);
        mfma_gemm_h<<<gH, blk, 0, stream>>>(a1p, w1bp, b1b, buf2, part, M, H, H, H);
        fin(g1b, be1b);
        bn_resid_relu_kernel<<<dim3(n4 / 256), blk, 0, stream>>>(buf0, buf2, scale, shift, n4, H, a0p, PSH);
        // 5. block 2
        mfma_gemm_h<<<gH, blk, 0, stream>>>(a0p, w2ap, b2a, buf1, part, M, H, H, H);
        fin(g2a, be2a);
        bn_apply_kernel<<<dim3(n4 / 256), blk, 0, stream>>>(buf1, scale, shift, 1, 0, n4, H, a1p, PSH);
        mfma_gemm_h<<<gH, blk, 0, stream>>>(a1p, w2bp, b2b, buf2, part, M, H, H, H);
        fin(g2b, be2b);
        bn_resid_relu_kernel<<<dim3(n4 / 256), blk, 0, stream>>>(buf0, buf2, scale, shift, n4, H, a0p, PSH);
        // 6. final linear (B planes padded to 256 rows; C guarded; no stats)
        mfma_gemm_h<<<gO, blk, 0, stream>>>(a0p, w3p, b3, buf3, nullptr, M, NO, H, NOP);
    } else {
        // fp32 fallback (colstats path)
        auto bnstep = [&](float* Y, const float* g, const float* be, int relu) {
            colstats_kernel<<<dim3(H / 256, NCH_OLD), blk, 0, stream>>>(Y, part, H, M / NCH_OLD);
            finalize_stats_kernel<<<dim3(H / 256), blk, 0, stream>>>(part, g, be, scale, shift, H, NCH_OLD, 1.0f / M);
            bn_apply_kernel<<<dim3(n4 / 256), blk, 0, stream>>>(Y, scale, shift, relu, 1, n4, H, nullptr, 0);
        };
        dim3 gH(H / 128, M / 128);
        dim3 gO((NO + 127) / 128, M / 128);
        gemm128<false, true><<<gH, blk, 0, stream>>>(x, W0, b0, buf0, M, H, K0P, K0, K0);
        bnstep(buf0, g0, be0, 1);
        gemm128<true, true><<<gH, blk, 0, stream>>>(buf0, W1a, b1a, buf1, M, H, H, H, H);
        bnstep(buf1, g1a, be1a, 1);
        gemm128<true, true><<<gH, blk, 0, stream>>>(buf1, W1b, b1b, buf2, M, H, H, H, H);
        bnstep(buf2, g1b, be1b, 0);
        resid_relu_kernel<<<dim3(n4 / 256), blk, 0, stream>>>(buf0, buf2, n4, nullptr, 0);
        gemm128<true, true><<<gH, blk, 0, stream>>>(buf0, W2a, b2a, buf1, M, H, H, H, H);
        bnstep(buf1, g2a, be2a, 1);
        gemm128<true, true><<<gH, blk, 0, stream>>>(buf1, W2b, b2b, buf2, M, H, H, H, H);
        bnstep(buf2, g2b, be2b, 0);
        resid_relu_kernel<<<dim3(n4 / 256), blk, 0, stream>>>(buf0, buf2, n4, nullptr, 0);
        gemm128<true, false><<<gO, blk, 0, stream>>>(buf0, W3, b3, buf3, M, NO, H, H, H);
    }

    // SVD epilogue -> d_out (fp32: rotmat then betas)
    svd_kernel<<<dim3((M * 24 + 255) / 256), blk, 0, stream>>>(buf3, (float*)d_out, M);
}

// Round 6
// 1023.421 us; speedup vs baseline: 1.9110x; 1.0905x over previous
//
#include <hip/hip_runtime.h>
#include <hip/hip_bf16.h>
#include <math.h>

typedef __attribute__((ext_vector_type(8))) _Float16 half8;
typedef __attribute__((ext_vector_type(4))) float floatx4;
typedef __attribute__((ext_vector_type(4))) unsigned short ushortx4;

__device__ __forceinline__ float hu2f(unsigned short u) {
    _Float16 h;
    __builtin_memcpy(&h, &u, 2);
    return (float)h;
}
__device__ __forceinline__ unsigned short f2hu(float x) {
    _Float16 h = (_Float16)x;  // v_cvt_f16_f32, RNE
    unsigned short u;
    __builtin_memcpy(&u, &h, 2);
    return u;
}
// 2-way fp16 split: a = h0 + h1 + r, |r| <= 2^-24 |a| (subtractions exact)
__device__ __forceinline__ void split2(float a, unsigned short& s0,
                                       unsigned short& s1) {
    s0 = f2hu(a);
    float r1 = a - hu2f(s0);   // exact
    s1 = f2hu(r1);
}

// global -> LDS direct copy, 16B per lane. LDS dest must be wave-uniform base.
typedef __attribute__((address_space(1))) unsigned int as1_u32;
typedef __attribute__((address_space(3))) unsigned int as3_u32;
__device__ __forceinline__ void gload16(const void* g, void* l) {
    __builtin_amdgcn_global_load_lds((const as1_u32*)g, (as3_u32*)l, 16, 0, 0);
}

// ---------------------------------------------------------------------------
// Weight transpose + 2-way fp16 split body: W[Ktrue,Ntrue] fp32 -> 2 planes
// [Nalloc][Kpad] fp16, zero-filled tails. One 32x32 tile per call.
// ---------------------------------------------------------------------------
__device__ __forceinline__ void wsplit_body(
    const float* __restrict__ W, unsigned short* __restrict__ out,
    int Ktrue, int Kpad, int Ntrue, int Nalloc, int k0, int n0,
    float (*T)[33], int tx, int ty)
{
#pragma unroll
    for (int i = 0; i < 4; i++) {
        int k = k0 + ty + 8 * i, n = n0 + tx;
        T[ty + 8 * i][tx] = (k < Ktrue && n < Ntrue) ? W[(size_t)k * Ntrue + n] : 0.f;
    }
    __syncthreads();
    const size_t PS = (size_t)Nalloc * Kpad;
#pragma unroll
    for (int i = 0; i < 4; i++) {
        int n = n0 + ty + 8 * i, k = k0 + tx;
        if (n < Nalloc) {
            unsigned short h0, h1;
            split2(T[tx][ty + 8 * i], h0, h1);
            size_t base = (size_t)n * Kpad + k;
            out[base] = h0;
            out[PS + base] = h1;
        }
    }
}

// All six weights in ONE launch. Segment table (compile-time, dims fixed):
//   [0,5184):   W0  (162 k-tiles x 32 n-tiles)
//   [5184,6208): W1a (32x32)   [6208,7232): W1b   [7232,8256): W2a
//   [8256,9280): W2b           [9280,9536): W3 (32 k-tiles x 8 n-tiles)
__global__ __launch_bounds__(256) void wsplit_all_kernel(
    const float* __restrict__ W0,  const float* __restrict__ W1a,
    const float* __restrict__ W1b, const float* __restrict__ W2a,
    const float* __restrict__ W2b, const float* __restrict__ W3,
    unsigned short* __restrict__ w0p,  unsigned short* __restrict__ w1ap,
    unsigned short* __restrict__ w1bp, unsigned short* __restrict__ w2ap,
    unsigned short* __restrict__ w2bp, unsigned short* __restrict__ w3p)
{
    __shared__ float T[32][33];
    const int tx = threadIdx.x & 31, ty = threadIdx.x >> 5;
    int bid = blockIdx.x;
    if (bid < 5184) {
        wsplit_body(W0, w0p, 5169, 5184, 1024, 1024,
                    (bid % 162) * 32, (bid / 162) * 32, T, tx, ty);
    } else if (bid < 6208) {
        int r = bid - 5184;
        wsplit_body(W1a, w1ap, 1024, 1024, 1024, 1024,
                    (r & 31) * 32, (r >> 5) * 32, T, tx, ty);
    } else if (bid < 7232) {
        int r = bid - 6208;
        wsplit_body(W1b, w1bp, 1024, 1024, 1024, 1024,
                    (r & 31) * 32, (r >> 5) * 32, T, tx, ty);
    } else if (bid < 8256) {
        int r = bid - 7232;
        wsplit_body(W2a, w2ap, 1024, 1024, 1024, 1024,
                    (r & 31) * 32, (r >> 5) * 32, T, tx, ty);
    } else if (bid < 9280) {
        int r = bid - 8256;
        wsplit_body(W2b, w2bp, 1024, 1024, 1024, 1024,
                    (r & 31) * 32, (r >> 5) * 32, T, tx, ty);
    } else {
        int r = bid - 9280;
        wsplit_body(W3, w3p, 1024, 1024, 226, 256,
                    (r & 31) * 32, (r >> 5) * 32, T, tx, ty);
    }
}

// ---------------------------------------------------------------------------
// Activation split: A[M,Ka] fp32 -> 2 fp16 planes [M][Kpad], zero-fill tail.
// ---------------------------------------------------------------------------
__global__ __launch_bounds__(256) void asplit2_kernel(
    const float* __restrict__ A, unsigned short* __restrict__ out,
    int Ka, int Kpad, int M)
{
    const int kq = Kpad >> 2;
    const int n = M * kq;
    int idx = blockIdx.x * 256 + threadIdx.x;
    if (idx >= n) return;
    int row = idx / kq, c4 = idx - row * kq;
    const size_t PS = (size_t)M * Kpad;
    ushortx4 o0, o1;
#pragma unroll
    for (int e = 0; e < 4; e++) {
        int col = c4 * 4 + e;
        float v = (col < Ka) ? A[(size_t)row * Ka + col] : 0.f;
        unsigned short a, b;
        split2(v, a, b);
        o0[e] = a; o1[e] = b;
    }
    size_t base = (size_t)row * Kpad + c4 * 4;
    *(ushortx4*)(out + base) = o0;
    *(ushortx4*)(out + PS + base) = o1;
}

// ---------------------------------------------------------------------------
// Pre-split 3-product fp16 MFMA GEMM (fp32-equivalent, err ~2^-23 rel):
//   C[M,N] = A @ B^T + bias, A planes [2][M][Kpad], B planes [2][Nb][Kpad].
// r4-proven core: 128x128 tile, BK=32, 4 waves, per wave 4x4 of 16x16x32
// MFMA; products A0B0 + A0B1 + A1B0 into one fp32 accumulator.
// Staging via global_load_lds w=16, linear LDS dest + pre-swizzled source,
// XOR key (row>>1)&3 on 16B slots -> 0 measured bank conflicts.
// r6: fused column-stats via atomicAdd into part[2][N] (part pre-zeroed;
// unique slot per bn-step, one memset for all). 128 adds/column total --
// negligible contention; order nondeterminism ~1e-7 rel.
// launch_bounds (256,3): (256,4) capped regs at 128 -> scratch spill (r3).
// ---------------------------------------------------------------------------
__global__ __launch_bounds__(256, 3) void mfma_gemm_h(
    const unsigned short* __restrict__ Apl,
    const unsigned short* __restrict__ Bpl,
    const float* __restrict__ bias, float* __restrict__ C,
    float* __restrict__ part,
    int M, int N, int Kpad, int Nb)
{
    __shared__ __align__(16) unsigned short As[2][128][32];
    __shared__ __align__(16) unsigned short Bs[2][128][32];

    const int tid = threadIdx.x;
    const int lane = tid & 63;
    const int wave = tid >> 6;
    const int wm = (wave & 1) * 64, wn = (wave >> 1) * 64;

    // XCD-aware bijective swizzle (all grids here are multiples of 8 blocks)
    const int gx = gridDim.x;
    const int nwg = gx * gridDim.y;
    const int id = blockIdx.y * gx + blockIdx.x;
    const int cpx = nwg >> 3;
    const int swz = (id & 7) * cpx + (id >> 3);
    const int bm = (swz / gx) * 128, bn = (swz % gx) * 128;

    const int l15 = lane & 15, q = lane >> 4;
    const size_t PSA = (size_t)M * Kpad;
    const size_t PSB = (size_t)Nb * Kpad;

    // staging: 32 chunks/block (2 mats x 2 planes x 8 row-blocks), 1 KiB each.
    const int srow = lane >> 2;
    const int gslot = (lane & 3) ^ ((srow >> 1) & 3);
    const int rkey = (l15 >> 1) & 3;  // read-side XOR key (row bits [2:1])

    floatx4 acc[4][4] = {};

    for (int k0 = 0; k0 < Kpad; k0 += 32) {
        // ---- stage: 8 global_load_lds per wave ----
#pragma unroll
        for (int i = 0; i < 8; i++) {
            int e = wave * 8 + i;              // 0..31
            int mat = e >> 4, p = (e >> 3) & 1, rb = (e & 7) << 4;
            if (mat == 0) {
                gload16(Apl + (size_t)p * PSA + (size_t)(bm + rb + srow) * Kpad
                            + (k0 + gslot * 8),
                        &As[p][rb][0]);
            } else {
                gload16(Bpl + (size_t)p * PSB + (size_t)(bn + rb + srow) * Kpad
                            + (k0 + gslot * 8),
                        &Bs[p][rb][0]);
            }
        }
        __syncthreads();  // compiler drains vmcnt before s_barrier

        // ---- fragments (swizzled read) + 3 products, shared accumulator ----
        half8 bfr[2][4];
#pragma unroll
        for (int p = 0; p < 2; p++)
#pragma unroll
            for (int ni = 0; ni < 4; ni++)
                bfr[p][ni] = *(const half8*)&Bs[p][wn + ni * 16 + l15][(q ^ rkey) * 8];
#pragma unroll
        for (int pa = 0; pa < 2; pa++) {
            half8 af[4];
#pragma unroll
            for (int mi = 0; mi < 4; mi++)
                af[mi] = *(const half8*)&As[pa][wm + mi * 16 + l15][(q ^ rkey) * 8];
#pragma unroll
            for (int pb = 0; pb + pa < 2; pb++) {  // (0,0),(0,1),(1,0)
#pragma unroll
                for (int mi = 0; mi < 4; mi++)
#pragma unroll
                    for (int ni = 0; ni < 4; ni++)
                        acc[mi][ni] = __builtin_amdgcn_mfma_f32_16x16x32_f16(
                            af[mi], bfr[pb][ni], acc[mi][ni], 0, 0, 0);
            }
        }
        __syncthreads();
    }

    // ---- epilogue: bias + store, with per-column (s, s2) accumulation ----
    float ps[4], ps2[4];
#pragma unroll
    for (int ni = 0; ni < 4; ni++) {
        int col = bn + wn + ni * 16 + l15;
        float s = 0.f, s2 = 0.f;
        if (col < N) {
            float bv = bias[col];
#pragma unroll
            for (int mi = 0; mi < 4; mi++) {
#pragma unroll
                for (int reg = 0; reg < 4; reg++) {
                    int row = bm + wm + mi * 16 + q * 4 + reg;
                    float v = acc[mi][ni][reg] + bv;
                    C[(size_t)row * N + col] = v;
                    s += v;
                    s2 += v * v;
                }
            }
        }
        ps[ni] = s; ps2[ni] = s2;
    }

    if (part) {  // uniform branch
        // reduce over q (lanes xor 16, 32): wave holds 64-row column sums
#pragma unroll
        for (int ni = 0; ni < 4; ni++) {
            ps[ni]  += __shfl_xor(ps[ni], 16);  ps[ni]  += __shfl_xor(ps[ni], 32);
            ps2[ni] += __shfl_xor(ps2[ni], 16); ps2[ni] += __shfl_xor(ps2[ni], 32);
        }
        if (q == 0) {  // 16 lanes x 2 row-half waves -> 2 atomics/col/block
#pragma unroll
            for (int ni = 0; ni < 4; ni++) {
                int col = bn + wn + ni * 16 + l15;
                if (col < N) {
                    atomicAdd(&part[col], ps[ni]);
                    atomicAdd(&part[N + col], ps2[ni]);
                }
            }
        }
    }
}

// ---------------------------------------------------------------------------
// fp32 fallback GEMM, used only if ws too small for planes.
// ---------------------------------------------------------------------------
template <bool AVEC, bool NV4>
__global__ __launch_bounds__(256) void gemm128(
    const float* __restrict__ A, const float* __restrict__ B,
    const float* __restrict__ bias, float* __restrict__ C,
    int M, int N, int Keff, int Ktrue, int Ka)
{
    __shared__ __align__(16) float Asm[16][132];
    __shared__ __align__(16) float Bsm[16][132];
    const int tid = threadIdx.x;
    const int bm = blockIdx.y * 128, bn = blockIdx.x * 128;
    const int tx = tid & 15, ty = tid >> 4;
    const int arow = tid >> 2, ac = tid & 3;
    const int bk = tid >> 4, bc = tid & 15;
    float acc[8][8] = {};
    for (int k0 = 0; k0 < Keff; k0 += 16) {
#pragma unroll
        for (int h = 0; h < 2; h++) {
            int rr = arow + h * 64;
            if (AVEC) {
                float4 v = *(const float4*)&A[(size_t)(bm + rr) * Ka + k0 + ac * 4];
                const float* pv = &v.x;
#pragma unroll
                for (int e = 0; e < 4; e++) Asm[ac * 4 + e][rr] = pv[e];
            } else {
#pragma unroll
                for (int e = 0; e < 4; e++) {
                    int kg = k0 + ac * 4 + e;
                    Asm[ac * 4 + e][rr] = (kg < Ka) ? A[(size_t)(bm + rr) * Ka + kg] : 0.f;
                }
            }
        }
        {
            int kg = k0 + bk;
            bool kok = (kg < Ktrue);
#pragma unroll
            for (int h = 0; h < 2; h++) {
                int cc = bc * 4 + h * 64;
                if (NV4) {
                    float4 v = {0.f, 0.f, 0.f, 0.f};
                    if (kok) v = *(const float4*)&B[(size_t)kg * N + bn + cc];
                    *(float4*)&Bsm[bk][cc] = v;
                } else {
#pragma unroll
                    for (int e = 0; e < 4; e++) {
                        int col = bn + cc + e;
                        Bsm[bk][cc + e] = (kok && col < N) ? B[(size_t)kg * N + col] : 0.f;
                    }
                }
            }
        }
        __syncthreads();
#pragma unroll
        for (int k = 0; k < 16; k++) {
            float4 a0 = *(const float4*)&Asm[k][ty * 4];
            float4 a1 = *(const float4*)&Asm[k][ty * 4 + 64];
            float4 b0 = *(const float4*)&Bsm[k][tx * 4];
            float4 b1 = *(const float4*)&Bsm[k][tx * 4 + 64];
            float av[8] = {a0.x, a0.y, a0.z, a0.w, a1.x, a1.y, a1.z, a1.w};
            float bv[8] = {b0.x, b0.y, b0.z, b0.w, b1.x, b1.y, b1.z, b1.w};
#pragma unroll
            for (int i = 0; i < 8; i++)
#pragma unroll
                for (int j = 0; j < 8; j++) acc[i][j] += av[i] * bv[j];
        }
        __syncthreads();
    }
#pragma unroll
    for (int i = 0; i < 8; i++) {
        int row = bm + (i < 4 ? ty * 4 + i : 64 + ty * 4 + (i - 4));
#pragma unroll
        for (int jh = 0; jh < 2; jh++)
#pragma unroll
            for (int e = 0; e < 4; e++) {
                int col = bn + jh * 64 + tx * 4 + e;
                if (NV4 || col < N)
                    C[(size_t)row * N + col] = acc[i][jh * 4 + e] + bias[col];
            }
    }
}

// ---------------------------------------------------------------------------
// fallback-path stats kernels (unused on main path)
__global__ __launch_bounds__(256) void colstats_kernel(
    const float* __restrict__ Y, float* __restrict__ part, int N, int rows)
{
    int c = blockIdx.x * 256 + threadIdx.x;
    int r0 = blockIdx.y * rows;
    const float* p = Y + (size_t)r0 * N + c;
    float s = 0.f, s2 = 0.f;
    for (int r = 0; r < rows; r++) {
        float v = p[(size_t)r * N];
        s += v;
        s2 += v * v;
    }
    part[(size_t)(blockIdx.y * 2 + 0) * N + c] = s;
    part[(size_t)(blockIdx.y * 2 + 1) * N + c] = s2;
}

__global__ void finalize_stats_kernel(
    const float* __restrict__ part, const float* __restrict__ g,
    const float* __restrict__ be, float* __restrict__ scale,
    float* __restrict__ shift, int N, int nchunk, float invM)
{
    int c = blockIdx.x * blockDim.x + threadIdx.x;
    if (c >= N) return;
    float s = 0.f, s2 = 0.f;
    for (int i = 0; i < nchunk; i++) {
        s  += part[(size_t)(2 * i + 0) * N + c];
        s2 += part[(size_t)(2 * i + 1) * N + c];
    }
    float m = s * invM;
    float v = s2 * invM - m * m;
    if (v < 0.f) v = 0.f;
    float sc = g[c] / sqrtf(v + 1e-5f);
    scale[c] = sc;
    shift[c] = be[c] - m * sc;
}

__global__ __launch_bounds__(256) void bn_apply_ss_kernel(
    float* __restrict__ Y, const float* __restrict__ scale,
    const float* __restrict__ shift, int do_relu, int n4, int N)
{
    int idx = blockIdx.x * 256 + threadIdx.x;
    if (idx >= n4) return;
    float4* Y4 = (float4*)Y;
    float4 v = Y4[idx];
    int c = (idx * 4) & (N - 1);
    v.x = v.x * scale[c + 0] + shift[c + 0];
    v.y = v.y * scale[c + 1] + shift[c + 1];
    v.z = v.z * scale[c + 2] + shift[c + 2];
    v.w = v.w * scale[c + 3] + shift[c + 3];
    if (do_relu) {
        v.x = fmaxf(v.x, 0.f); v.y = fmaxf(v.y, 0.f);
        v.z = fmaxf(v.z, 0.f); v.w = fmaxf(v.w, 0.f);
    }
    Y4[idx] = v;
}

// ---------------------------------------------------------------------------
// main-path bn: per-thread scale/shift from part[2][N] (exact finalize math)
// ---------------------------------------------------------------------------
__device__ __forceinline__ void bn_coeff(
    const float* __restrict__ part, const float* __restrict__ g,
    const float* __restrict__ be, int c, float invM, float* sc, float* sh)
{
    float4 s4 = *(const float4*)&part[c];
    float4 q4 = *(const float4*)&part[1024 + c];
    float4 g4 = *(const float4*)&g[c];
    float4 b4 = *(const float4*)&be[c];
    const float* sp = &s4.x; const float* qp = &q4.x;
    const float* gp = &g4.x; const float* bp = &b4.x;
#pragma unroll
    for (int e = 0; e < 4; e++) {
        float m = sp[e] * invM;
        float v = qp[e] * invM - m * m;
        if (v < 0.f) v = 0.f;
        float s = gp[e] / sqrtf(v + 1e-5f);
        sc[e] = s;
        sh[e] = bp[e] - m * s;
    }
}

// bn-apply; optional fp32 write-back (write_y) and fp16 plane emission
__global__ __launch_bounds__(256) void bn_apply_kernel(
    float* __restrict__ Y, const float* __restrict__ part,
    const float* __restrict__ g, const float* __restrict__ be,
    int do_relu, int write_y, int n4, float invM,
    unsigned short* __restrict__ plane, size_t PS)
{
    int idx = blockIdx.x * 256 + threadIdx.x;
    if (idx >= n4) return;
    float4* Y4 = (float4*)Y;
    float4 v = Y4[idx];
    int c = (idx * 4) & 1023;
    float sc[4], sh[4];
    bn_coeff(part, g, be, c, invM, sc, sh);
    v.x = v.x * sc[0] + sh[0];
    v.y = v.y * sc[1] + sh[1];
    v.z = v.z * sc[2] + sh[2];
    v.w = v.w * sc[3] + sh[3];
    if (do_relu) {
        v.x = fmaxf(v.x, 0.f); v.y = fmaxf(v.y, 0.f);
        v.z = fmaxf(v.z, 0.f); v.w = fmaxf(v.w, 0.f);
    }
    if (write_y) Y4[idx] = v;
    if (plane) {
        float vv[4] = {v.x, v.y, v.z, v.w};
        ushortx4 o0, o1;
#pragma unroll
        for (int e = 0; e < 4; e++) {
            unsigned short a, b;
            split2(vv[e], a, b);
            o0[e] = a; o1[e] = b;
        }
        size_t base = (size_t)idx * 4;
        *(ushortx4*)(plane + base) = o0;
        *(ushortx4*)(plane + PS + base) = o1;
    }
}

// fused: H = relu(H + bn(T)); emits planes of H.
__global__ __launch_bounds__(256) void bn_resid_relu_kernel(
    float* __restrict__ Hb, const float* __restrict__ T,
    const float* __restrict__ part, const float* __restrict__ g,
    const float* __restrict__ be, int n4, float invM,
    unsigned short* __restrict__ plane, size_t PS)
{
    int idx = blockIdx.x * 256 + threadIdx.x;
    if (idx >= n4) return;
    float4 h = ((float4*)Hb)[idx];
    float4 t = ((const float4*)T)[idx];
    int c = (idx * 4) & 1023;
    float sc[4], sh[4];
    bn_coeff(part, g, be, c, invM, sc, sh);
    t.x = t.x * sc[0] + sh[0];
    t.y = t.y * sc[1] + sh[1];
    t.z = t.z * sc[2] + sh[2];
    t.w = t.w * sc[3] + sh[3];
    h.x = fmaxf(h.x + t.x, 0.f);
    h.y = fmaxf(h.y + t.y, 0.f);
    h.z = fmaxf(h.z + t.z, 0.f);
    h.w = fmaxf(h.w + t.w, 0.f);
    ((float4*)Hb)[idx] = h;
    if (plane) {
        float vv[4] = {h.x, h.y, h.z, h.w};
        ushortx4 o0, o1;
#pragma unroll
        for (int e = 0; e < 4; e++) {
            unsigned short a, b;
            split2(vv[e], a, b);
            o0[e] = a; o1[e] = b;
        }
        size_t base = (size_t)idx * 4;
        *(ushortx4*)(plane + base) = o0;
        *(ushortx4*)(plane + PS + base) = o1;
    }
}

__global__ __launch_bounds__(256) void resid_relu_kernel(
    float* __restrict__ Hb, const float* __restrict__ T, int n4)
{
    int idx = blockIdx.x * 256 + threadIdx.x;
    if (idx >= n4) return;
    float4 h = ((float4*)Hb)[idx];
    float4 t = ((const float4*)T)[idx];
    h.x = fmaxf(h.x + t.x, 0.f);
    h.y = fmaxf(h.y + t.y, 0.f);
    h.z = fmaxf(h.z + t.z, 0.f);
    h.w = fmaxf(h.w + t.w, 0.f);
    ((float4*)Hb)[idx] = h;
}

// ---------------------------------------------------------------------------
// O = det(R)*R, R = polar(M). Jacobi on M^T M in fp64. fp32 output.
// ---------------------------------------------------------------------------
__global__ __launch_bounds__(256) void svd_kernel(
    const float* __restrict__ O3, float* __restrict__ out, int nb)
{
    int gidx = blockIdx.x * 256 + threadIdx.x;
    if (gidx >= nb * 24) return;
    int row = gidx / 24;
    int j = gidx - row * 24;
    const float* rowp = O3 + (size_t)row * 226;
    const float* src = rowp + j * 9;

    double m[3][3];
#pragma unroll
    for (int r = 0; r < 3; r++)
#pragma unroll
        for (int c = 0; c < 3; c++) m[r][c] = (double)src[r * 3 + c];

    double a[3][3];
#pragma unroll
    for (int r = 0; r < 3; r++)
#pragma unroll
        for (int c = 0; c < 3; c++) {
            double s = 0.0;
#pragma unroll
            for (int k = 0; k < 3; k++) s += m[k][r] * m[k][c];
            a[r][c] = s;
        }

    double V[3][3] = {{1, 0, 0}, {0, 1, 0}, {0, 0, 1}};
    const int PP[3] = {0, 0, 1}, QQ[3] = {1, 2, 2};
    for (int sweep = 0; sweep < 8; sweep++) {
        for (int r3 = 0; r3 < 3; r3++) {
            int p = PP[r3], q = QQ[r3];
            double apq = a[p][q];
            if (fabs(apq) < 1e-60) continue;
            double tau = (a[q][q] - a[p][p]) / (2.0 * apq);
            double t = ((tau >= 0.0) ? 1.0 : -1.0) / (fabs(tau) + sqrt(1.0 + tau * tau));
            double c = 1.0 / sqrt(1.0 + t * t);
            double s = t * c;
#pragma unroll
            for (int k = 0; k < 3; k++) {
                double xp = a[p][k], xq = a[q][k];
                a[p][k] = c * xp - s * xq;
                a[q][k] = s * xp + c * xq;
            }
#pragma unroll
            for (int k = 0; k < 3; k++) {
                double xp = a[k][p], xq = a[k][q];
                a[k][p] = c * xp - s * xq;
                a[k][q] = s * xp + c * xq;
            }
#pragma unroll
            for (int k = 0; k < 3; k++) {
                double xp = V[k][p], xq = V[k][q];
                V[k][p] = c * xp - s * xq;
                V[k][q] = s * xp + c * xq;
            }
        }
    }

    double lam[3] = {a[0][0], a[1][1], a[2][2]};
    int i3 = 0;
    if (lam[1] < lam[i3]) i3 = 1;
    if (lam[2] < lam[i3]) i3 = 2;
    int i1 = (i3 + 1) % 3, i2 = (i3 + 2) % 3;

    double v1[3], v2[3], v3[3];
#pragma unroll
    for (int k = 0; k < 3; k++) {
        v1[k] = V[k][i1];
        v2[k] = V[k][i2];
        v3[k] = V[k][i3];
    }

    double u1[3], u2[3];
#pragma unroll
    for (int r = 0; r < 3; r++)
        u1[r] = m[r][0] * v1[0] + m[r][1] * v1[1] + m[r][2] * v1[2];
    double n1 = sqrt(u1[0] * u1[0] + u1[1] * u1[1] + u1[2] * u1[2]);
    double inv1 = (n1 > 1e-150) ? 1.0 / n1 : 0.0;
#pragma unroll
    for (int r = 0; r < 3; r++) u1[r] *= inv1;

#pragma unroll
    for (int r = 0; r < 3; r++)
        u2[r] = m[r][0] * v2[0] + m[r][1] * v2[1] + m[r][2] * v2[2];
    double d12 = u1[0] * u2[0] + u1[1] * u2[1] + u1[2] * u2[2];
#pragma unroll
    for (int r = 0; r < 3; r++) u2[r] -= d12 * u1[r];
    double n2 = sqrt(u2[0] * u2[0] + u2[1] * u2[1] + u2[2] * u2[2]);
    double inv2 = (n2 > 1e-150) ? 1.0 / n2 : 0.0;
#pragma unroll
    for (int r = 0; r < 3; r++) u2[r] *= inv2;

    double detM = m[0][0] * (m[1][1] * m[2][2] - m[1][2] * m[2][1])
                - m[0][1] * (m[1][0] * m[2][2] - m[1][2] * m[2][0])
                + m[0][2] * (m[1][0] * m[2][1] - m[1][1] * m[2][0]);
    double sgn = (detM >= 0.0) ? 1.0 : -1.0;
    double detV = v1[0] * (v2[1] * v3[2] - v2[2] * v3[1])
                - v1[1] * (v2[0] * v3[2] - v2[2] * v3[0])
                + v1[2] * (v2[0] * v3[1] - v2[1] * v3[0]);
    double sv = (detV >= 0.0) ? 1.0 : -1.0;

    double u3[3];
    u3[0] = sgn * sv * (u1[1] * u2[2] - u1[2] * u2[1]);
    u3[1] = sgn * sv * (u1[2] * u2[0] - u1[0] * u2[2]);
    u3[2] = sgn * sv * (u1[0] * u2[1] - u1[1] * u2[0]);

    size_t rot_base = (size_t)gidx * 9;
    size_t beta_base = (size_t)nb * 24 * 9 + (size_t)row * 10;
#pragma unroll
    for (int r = 0; r < 3; r++)
#pragma unroll
        for (int c = 0; c < 3; c++)
            out[rot_base + r * 3 + c] =
                (float)(sgn * (u1[r] * v1[c] + u2[r] * v2[c] + u3[r] * v3[c]));

    if (j < 10) out[beta_base + j] = rowp[216 + j];
}

// ---------------------------------------------------------------------------
extern "C" void kernel_launch(void* const* d_in, const int* in_sizes, int n_in,
                              void* d_out, int out_size, void* d_ws, size_t ws_size,
                              hipStream_t stream)
{
    const float* x    = (const float*)d_in[0];
    const float* W0   = (const float*)d_in[1];
    const float* b0   = (const float*)d_in[2];
    const float* g0   = (const float*)d_in[3];
    const float* be0  = (const float*)d_in[4];
    const float* W1a  = (const float*)d_in[5];
    const float* b1a  = (const float*)d_in[6];
    const float* g1a  = (const float*)d_in[7];
    const float* be1a = (const float*)d_in[8];
    const float* W1b  = (const float*)d_in[9];
    const float* b1b  = (const float*)d_in[10];
    const float* g1b  = (const float*)d_in[11];
    const float* be1b = (const float*)d_in[12];
    const float* W2a  = (const float*)d_in[13];
    const float* b2a  = (const float*)d_in[14];
    const float* g2a  = (const float*)d_in[15];
    const float* be2a = (const float*)d_in[16];
    const float* W2b  = (const float*)d_in[17];
    const float* b2b  = (const float*)d_in[18];
    const float* g2b  = (const float*)d_in[19];
    const float* be2b = (const float*)d_in[20];
    const float* W3   = (const float*)d_in[21];
    const float* b3   = (const float*)d_in[22];

    const int M = 8192, H = 1024, K0 = 5169, K0P = 5184, NO = 226, NOP = 256;
    const int NCH_OLD = 32;   // fallback colstats chunking

    const size_t SZ_ACT  = (size_t)M * H;
    const size_t SZ_O3   = (size_t)M * NO;
    const size_t SZ_PART = (size_t)2 * NCH_OLD * H;   // fallback needs the most

    float* ws   = (float*)d_ws;
    float* buf0 = ws;
    float* buf1 = buf0 + SZ_ACT;
    float* buf2 = buf1 + SZ_ACT;
    float* buf3 = buf2 + SZ_ACT;
    float* parts = buf3 + SZ_O3;            // main: 6 slots x [2][H]; fb: chunked
    float* scale = parts + SZ_PART;
    float* shift = scale + H;
    size_t float_base = 3 * SZ_ACT + SZ_O3 + SZ_PART + 2 * H + 16;

    // fp16 weight planes (2 per weight), [Nalloc][Kpad]
    unsigned short* pl = (unsigned short*)(ws + float_base);
    unsigned short* w0p  = pl;
    unsigned short* w1ap = w0p  + (size_t)2 * H * K0P;
    unsigned short* w1bp = w1ap + (size_t)2 * H * H;
    unsigned short* w2ap = w1bp + (size_t)2 * H * H;
    unsigned short* w2bp = w2ap + (size_t)2 * H * H;
    unsigned short* w3p  = w2bp + (size_t)2 * H * H;
    // activation planes
    unsigned short* xp  = w3p + (size_t)2 * NOP * H;
    unsigned short* a0p = xp  + (size_t)2 * M * K0P;
    unsigned short* a1p = a0p + (size_t)2 * M * H;
    unsigned short* pend = a1p + (size_t)2 * M * H;

    size_t bytes_new = float_base * 4 + (size_t)(pend - pl) * 2;
    bool use_new = ws_size >= bytes_new;

    dim3 blk(256);
    const int n4 = M * H / 4;
    const size_t PSH = (size_t)M * H;
    const float invM = 1.0f / M;

    if (use_new) {
        // part slot per bn step
        float* p0 = parts + 0 * 2 * H;
        float* p1 = parts + 1 * 2 * H;
        float* p2 = parts + 2 * 2 * H;
        float* p3 = parts + 3 * 2 * H;
        float* p4 = parts + 4 * 2 * H;
        hipMemsetAsync(parts, 0, (size_t)6 * 2 * H * sizeof(float), stream);

        // 1. all weight planes, one launch
        wsplit_all_kernel<<<dim3(9536), blk, 0, stream>>>(
            W0, W1a, W1b, W2a, W2b, W3, w0p, w1ap, w1bp, w2ap, w2bp, w3p);
        // 2. input planes
        asplit2_kernel<<<dim3(M * (K0P / 4) / 256), blk, 0, stream>>>(x, xp, K0, K0P, M);

        dim3 gH(H / 128, M / 128);     // 512 blocks
        dim3 gO(NOP / 128, M / 128);   // 128 blocks

        // 3. layer 0
        mfma_gemm_h<<<gH, blk, 0, stream>>>(xp, w0p, b0, buf0, p0, M, H, K0P, H);
        bn_apply_kernel<<<dim3(n4 / 256), blk, 0, stream>>>(buf0, p0, g0, be0, 1, 1, n4, invM, a0p, PSH);
        // 4. block 1
        mfma_gemm_h<<<gH, blk, 0, stream>>>(a0p, w1ap, b1a, buf1, p1, M, H, H, H);
        bn_apply_kernel<<<dim3(n4 / 256), blk, 0, stream>>>(buf1, p1, g1a, be1a, 1, 0, n4, invM, a1p, PSH);
        mfma_gemm_h<<<gH, blk, 0, stream>>>(a1p, w1bp, b1b, buf2, p2, M, H, H, H);
        bn_resid_relu_kernel<<<dim3(n4 / 256), blk, 0, stream>>>(buf0, buf2, p2, g1b, be1b, n4, invM, a0p, PSH);
        // 5. block 2
        mfma_gemm_h<<<gH, blk, 0, stream>>>(a0p, w2ap, b2a, buf1, p3, M, H, H, H);
        bn_apply_kernel<<<dim3(n4 / 256), blk, 0, stream>>>(buf1, p3, g2a, be2a, 1, 0, n4, invM, a1p, PSH);
        mfma_gemm_h<<<gH, blk, 0, stream>>>(a1p, w2bp, b2b, buf2, p4, M, H, H, H);
        bn_resid_relu_kernel<<<dim3(n4 / 256), blk, 0, stream>>>(buf0, buf2, p4, g2b, be2b, n4, invM, a0p, PSH);
        // 6. final linear (B planes padded to 256 rows; C guarded; no stats)
        mfma_gemm_h<<<gO, blk, 0, stream>>>(a0p, w3p, b3, buf3, nullptr, M, NO, H, NOP);
    } else {
        // fp32 fallback (colstats path)
        auto bnstep = [&](float* Y, const float* g, const float* be, int relu) {
            colstats_kernel<<<dim3(H / 256, NCH_OLD), blk, 0, stream>>>(Y, parts, H, M / NCH_OLD);
            finalize_stats_kernel<<<dim3(H / 256), blk, 0, stream>>>(parts, g, be, scale, shift, H, NCH_OLD, invM);
            bn_apply_ss_kernel<<<dim3(n4 / 256), blk, 0, stream>>>(Y, scale, shift, relu, n4, H);
        };
        dim3 gH(H / 128, M / 128);
        dim3 gO((NO + 127) / 128, M / 128);
        gemm128<false, true><<<gH, blk, 0, stream>>>(x, W0, b0, buf0, M, H, K0P, K0, K0);
        bnstep(buf0, g0, be0, 1);
        gemm128<true, true><<<gH, blk, 0, stream>>>(buf0, W1a, b1a, buf1, M, H, H, H, H);
        bnstep(buf1, g1a, be1a, 1);
        gemm128<true, true><<<gH, blk, 0, stream>>>(buf1, W1b, b1b, buf2, M, H, H, H, H);
        bnstep(buf2, g1b, be1b, 0);
        resid_relu_kernel<<<dim3(n4 / 256), blk, 0, stream>>>(buf0, buf2, n4);
        gemm128<true, true><<<gH, blk, 0, stream>>>(buf0, W2a, b2a, buf1, M, H, H, H, H);
        bnstep(buf1, g2a, be2a, 1);
        gemm128<true, true><<<gH, blk, 0, stream>>>(buf1, W2b, b2b, buf2, M, H, H, H, H);
        bnstep(buf2, g2b, be2b, 0);
        resid_relu_kernel<<<dim3(n4 / 256), blk, 0, stream>>>(buf0, buf2, n4);
        gemm128<true, false><<<gO, blk, 0, stream>>>(buf0, W3, b3, buf3, M, NO, H, H, H);
    }

    // SVD epilogue -> d_out (fp32: rotmat then betas)
    svd_kernel<<<dim3((M * 24 + 255) / 256), blk, 0, stream>>>(buf3, (float*)d_out, M);
}